// Round 1
// baseline (263.519 us; speedup 1.0000x reference)
//
#include <hip/hip_runtime.h>

#define S_LEN 2048
#define D_DIM 1024
#define NH    16
#define HD    64
#define BATCH 4
#define M_ROWS 8192

typedef __attribute__((ext_vector_type(8))) short bf16x8;   // 8 bf16 = 4 VGPR
typedef __attribute__((ext_vector_type(4))) float f32x4;
typedef __attribute__((ext_vector_type(8))) unsigned short u16x8;

__device__ __forceinline__ unsigned short f2bf(float f) {
    unsigned u = __builtin_bit_cast(unsigned, f);
    u = (u + 0x7fffu + ((u >> 16) & 1u)) >> 16;   // RNE
    return (unsigned short)u;
}
// round-half-up pack of two f32 -> packed bf16x2 (bias cancels: l from same P)
__device__ __forceinline__ unsigned pack2(float a, float b) {
    unsigned ua = __builtin_bit_cast(unsigned, a);
    unsigned ub = __builtin_bit_cast(unsigned, b);
    return ((ua + 0x8000u) >> 16) | ((ub + 0x8000u) & 0xffff0000u);
}

__device__ __forceinline__ void gload16(const void* g, void* l) {
    __builtin_amdgcn_global_load_lds((const __attribute__((address_space(1))) unsigned*)g,
                                     (__attribute__((address_space(3))) unsigned*)l,
                                     16, 0, 0);
}

template<int N> __device__ __forceinline__ void vmwait() {
    static_assert(N == 0 || N == 3 || N == 6 || N == 9, "unexpected vmcnt");
    if constexpr (N == 0) asm volatile("s_waitcnt vmcnt(0)" ::: "memory");
    if constexpr (N == 3) asm volatile("s_waitcnt vmcnt(3)" ::: "memory");
    if constexpr (N == 6) asm volatile("s_waitcnt vmcnt(6)" ::: "memory");
    if constexpr (N == 9) asm volatile("s_waitcnt vmcnt(9)" ::: "memory");
}

// ---------------------------------------------------------------------------
// Merged prep: blocks [0,4096) cast x fp32->bf16; blocks [4096,5120) build
// W^T bf16 (wq pre-scaled by 0.125*log2(e)). One launch instead of two.
// ---------------------------------------------------------------------------
__global__ __launch_bounds__(256) void prep_k(const float* __restrict__ x,
                                              const float* __restrict__ w0, const float* __restrict__ w1,
                                              const float* __restrict__ w2, const float* __restrict__ w3,
                                              unsigned short* __restrict__ xbf,
                                              unsigned short* __restrict__ o0, unsigned short* __restrict__ o1,
                                              unsigned short* __restrict__ o2, unsigned short* __restrict__ o3) {
    __shared__ float sT[64][65];
    const int t = threadIdx.x;
    if (blockIdx.x < 4096) {
        size_t i = (size_t)blockIdx.x * 256 + t;
        const float4* xf = (const float4*)x;
        float4 a = xf[2 * i], b = xf[2 * i + 1];
        u16x8 v;
        v[0] = f2bf(a.x); v[1] = f2bf(a.y); v[2] = f2bf(a.z); v[3] = f2bf(a.w);
        v[4] = f2bf(b.x); v[5] = f2bf(b.y); v[6] = f2bf(b.z); v[7] = f2bf(b.w);
        *(u16x8*)(xbf + i * 8) = v;
        return;
    }
    const int wb = blockIdx.x - 4096;          // 0..1023
    const int z = wb >> 8;                     // weight index
    const float* w; unsigned short* o;
    switch (z) {
        case 0: w = w0; o = o0; break;
        case 1: w = w1; o = o1; break;
        case 2: w = w2; o = o2; break;
        default: w = w3; o = o3; break;
    }
    const float sc = (z == 0) ? 0.18033688011112042f : 1.0f;
    const int n0 = (wb & 15) * 64, k0 = ((wb >> 4) & 15) * 64;
    const int r = t >> 4, cq = t & 15;
#pragma unroll
    for (int it = 0; it < 4; ++it) {
        int k = r + it * 16;
        float4 v = *(const float4*)&w[(size_t)(k0 + k) * D_DIM + n0 + cq * 4];
        sT[k][cq * 4 + 0] = v.x; sT[k][cq * 4 + 1] = v.y;
        sT[k][cq * 4 + 2] = v.z; sT[k][cq * 4 + 3] = v.w;
    }
    __syncthreads();
    const int n = t >> 2, ch = t & 3;
    union { unsigned short s[8]; uint4 v; } p0, p1;
#pragma unroll
    for (int j = 0; j < 8; ++j) p0.s[j] = f2bf(sT[ch * 16 + j][n] * sc);
#pragma unroll
    for (int j = 0; j < 8; ++j) p1.s[j] = f2bf(sT[ch * 16 + 8 + j][n] * sc);
    *(uint4*)&o[(size_t)(n0 + n) * D_DIM + k0 + ch * 16]     = p0.v;
    *(uint4*)&o[(size_t)(n0 + n) * D_DIM + k0 + ch * 16 + 8] = p1.v;
}

// ---------------------------------------------------------------------------
// Pipelined GEMM core (T3+T4+T5): tile 128x256, BK=32, 8 waves (2M x 4N),
// 4-deep LDS ring (96KB -> 1 block/CU), counted vmcnt keeps 3 K-tiles of
// global_load_lds (9 instr/wave) in flight ACROSS barriers -- never drained
// to 0 in the main loop. Per phase: 3 gload issue, vmcnt(9), barrier,
// 8 ds_read_b128, 16 MFMA under setprio(1), lgkmcnt(0), barrier.
// XOR chunk swizzle g = j ^ ((row>>1)&3): 16 lanes cover all 8 16B slots
// per 128B -> 2-way (free) on every ds_read_b128.
// ---------------------------------------------------------------------------
static constexpr int GBM = 128;   // M tile
static constexpr int GBN = 256;   // N tile
static constexpr int GNT = 32;    // K tiles (1024/32)

__device__ __forceinline__ void gemm_pipe(const unsigned short* __restrict__ A,
                                          const unsigned short* __restrict__ Bt,
                                          unsigned short* sA, unsigned short* sB,
                                          int m0, int n0, int t,
                                          f32x4 (&acc)[4][4])
{
    const int lane = t & 63, w = t >> 6;
    const int mm = lane & 15, quad = lane >> 4;
    const int wm = w >> 2, wn = w & 3;

    // per-thread pre-swizzled global source pointers
    const unsigned short* asrc;
    {
        int r = t >> 2, j = t & 3, g = j ^ ((r >> 1) & 3);
        asrc = A + (size_t)(m0 + r) * D_DIM + g * 8;
    }
    const unsigned short* bsrc[2];
#pragma unroll
    for (int i = 0; i < 2; ++i) {
        int r = i * 128 + (t >> 2), j = t & 3, g = j ^ ((r >> 1) & 3);
        bsrc[i] = Bt + (size_t)(n0 + r) * D_DIM + g * 8;
    }

    auto stage = [&](int buf, int kt) {
        const int ko = kt * 32;
        gload16(asrc + ko, sA + buf * (GBM * 32) + t * 8);
#pragma unroll
        for (int i = 0; i < 2; ++i)
            gload16(bsrc[i] + ko, sB + buf * (GBN * 32) + i * 4096 + t * 8);
    };

    auto compute = [&](int buf) {
        bf16x8 af[4], bfr[4];
#pragma unroll
        for (int mi = 0; mi < 4; ++mi) {
            int m = wm * 64 + mi * 16 + mm;
            int slot = quad ^ ((m >> 1) & 3);
            af[mi] = *(const bf16x8*)&sA[buf * (GBM * 32) + m * 32 + slot * 8];
        }
#pragma unroll
        for (int ni = 0; ni < 4; ++ni) {
            int n = wn * 64 + ni * 16 + mm;
            int slot = quad ^ ((n >> 1) & 3);
            bfr[ni] = *(const bf16x8*)&sB[buf * (GBN * 32) + n * 32 + slot * 8];
        }
        __builtin_amdgcn_s_setprio(1);
#pragma unroll
        for (int mi = 0; mi < 4; ++mi)
#pragma unroll
            for (int ni = 0; ni < 4; ++ni)
                acc[mi][ni] = __builtin_amdgcn_mfma_f32_16x16x32_bf16(af[mi], bfr[ni], acc[mi][ni], 0, 0, 0);
        __builtin_amdgcn_s_setprio(0);
    };

    // prologue: tiles 0..2 into bufs 0..2 (9 loads in flight)
#pragma unroll
    for (int tt = 0; tt < 3; ++tt) stage(tt, tt);

#pragma unroll 4
    for (int kt = 0; kt < 28; ++kt) {
        stage((kt + 3) & 3, kt + 3);          // writes buf freed at end of kt-1
        vmwait<9>();                          // tile kt landed (3 tiles stay in flight)
        __builtin_amdgcn_s_barrier();         // ... in every wave
        asm volatile("" ::: "memory");
        compute(kt & 3);
        asm volatile("s_waitcnt lgkmcnt(0)" ::: "memory");   // my ds_reads retired
        __builtin_amdgcn_s_barrier();         // everyone done reading buf kt&3
    }
    // kt = 28: last stage (tile 31 -> buf 3)
    stage(3, 31);
    vmwait<9>();
    __builtin_amdgcn_s_barrier();
    asm volatile("" ::: "memory");
    compute(0);
    asm volatile("s_waitcnt lgkmcnt(0)" ::: "memory");
    __builtin_amdgcn_s_barrier();
    // tails: derived waits 6 -> 3 -> 0
    vmwait<6>();
    __builtin_amdgcn_s_barrier();
    asm volatile("" ::: "memory");
    compute(1);
    asm volatile("s_waitcnt lgkmcnt(0)" ::: "memory");
    __builtin_amdgcn_s_barrier();
    vmwait<3>();
    __builtin_amdgcn_s_barrier();
    asm volatile("" ::: "memory");
    compute(2);
    asm volatile("s_waitcnt lgkmcnt(0)" ::: "memory");
    __builtin_amdgcn_s_barrier();
    vmwait<0>();
    __builtin_amdgcn_s_barrier();
    asm volatile("" ::: "memory");
    compute(3);
}

// ---------------------------------------------------------------------------
// Fused QKV GEMM. n covers [Wq|Wk|Wv] (N=3072, 256-wide tiles never cross a
// weight boundary). Q,K written bf16 row-major; V written directly transposed
// per head into vt[bh][hd][s].  Grid 12 x 64 = 768 blocks = 3 x 256 CUs.
// ---------------------------------------------------------------------------
__global__ __launch_bounds__(512, 2) void gemmqkv_k(const unsigned short* __restrict__ A,
                                                    const unsigned short* __restrict__ Bt,
                                                    unsigned short* __restrict__ qb,
                                                    unsigned short* __restrict__ kb,
                                                    unsigned short* __restrict__ vt)
{
    __shared__ unsigned short sA[4 * GBM * 32];   // 32KB
    __shared__ unsigned short sB[4 * GBN * 32];   // 64KB
    const int t = threadIdx.x;
    const int m0 = blockIdx.y * GBM, n0 = blockIdx.x * GBN;

    f32x4 acc[4][4];
#pragma unroll
    for (int i = 0; i < 4; ++i)
#pragma unroll
        for (int j = 0; j < 4; ++j) acc[i][j] = (f32x4){0.f, 0.f, 0.f, 0.f};

    gemm_pipe(A, Bt, sA, sB, m0, n0, t, acc);

    const int lane = t & 63, w = t >> 6;
    const int mm = lane & 15, quad = lane >> 4;
    const int wm = w >> 2, wn = w & 3;
    const int widx = n0 >> 10, nl0 = n0 & 1023;

    if (widx == 2) {
        // V: write transposed per head
#pragma unroll
        for (int mi = 0; mi < 4; ++mi) {
            int rglob = m0 + wm * 64 + mi * 16 + quad * 4;
            int bb = rglob >> 11, ss = rglob & (S_LEN - 1);
#pragma unroll
            for (int ni = 0; ni < 4; ++ni) {
                int c = nl0 + wn * 64 + ni * 16 + mm;
                int h = c >> 6, hd = c & 63;
                union { unsigned short s[4]; unsigned long long ll; } pk;
#pragma unroll
                for (int r = 0; r < 4; ++r) pk.s[r] = f2bf(acc[mi][ni][r]);
                *(unsigned long long*)&vt[((size_t)(bb * NH + h) * HD + hd) * S_LEN + ss] = pk.ll;
            }
        }
    } else {
        unsigned short* outp = widx ? kb : qb;
#pragma unroll
        for (int mi = 0; mi < 4; ++mi)
#pragma unroll
            for (int ni = 0; ni < 4; ++ni)
#pragma unroll
                for (int r = 0; r < 4; ++r)
                    outp[(size_t)(m0 + wm * 64 + mi * 16 + quad * 4 + r) * D_DIM +
                         nl0 + wn * 64 + ni * 16 + mm] = f2bf(acc[mi][ni][r]);
    }
}

// ---------------------------------------------------------------------------
// Output GEMM: out_fp32 = ctx_bf16 * WoT^T.  Grid 4 x 64 = 256 blocks.
// ---------------------------------------------------------------------------
__global__ __launch_bounds__(512, 2) void gemmo_k(const unsigned short* __restrict__ A,
                                                  const unsigned short* __restrict__ Bt,
                                                  float* __restrict__ C)
{
    __shared__ unsigned short sA[4 * GBM * 32];
    __shared__ unsigned short sB[4 * GBN * 32];
    const int t = threadIdx.x;
    const int m0 = blockIdx.y * GBM, n0 = blockIdx.x * GBN;

    f32x4 acc[4][4];
#pragma unroll
    for (int i = 0; i < 4; ++i)
#pragma unroll
        for (int j = 0; j < 4; ++j) acc[i][j] = (f32x4){0.f, 0.f, 0.f, 0.f};

    gemm_pipe(A, Bt, sA, sB, m0, n0, t, acc);

    const int lane = t & 63, w = t >> 6;
    const int mm = lane & 15, quad = lane >> 4;
    const int wm = w >> 2, wn = w & 3;

#pragma unroll
    for (int mi = 0; mi < 4; ++mi)
#pragma unroll
        for (int ni = 0; ni < 4; ++ni)
#pragma unroll
            for (int r = 0; r < 4; ++r)
                C[(size_t)(m0 + wm * 64 + mi * 16 + quad * 4 + r) * D_DIM +
                  n0 + wn * 64 + ni * 16 + mm] = acc[mi][ni][r];
}

// ---------------------------------------------------------------------------
// Fused causal flash attention (round-4 verified config: 74.5 us).
// 512 threads (8 waves), 16 q-rows/wave, block covers strips {qt, 15-qt}
// (uniform 34 k-tiles of 64 keys). K/V^T double-buffered, prefetch issued
// right after the per-tile barrier (long compute phase hides the drain).
// l computed via MFMA against all-ones B; sP rows are wave-private.
// ---------------------------------------------------------------------------
__global__ __launch_bounds__(512, 4) void attn_k(const unsigned short* __restrict__ Q,
                                                 const unsigned short* __restrict__ K,
                                                 const unsigned short* __restrict__ Vt,
                                                 unsigned short* __restrict__ ctx)
{
    __shared__ unsigned short sK [2][64 * 64];   // [buf][key][hd]   2x8KB
    __shared__ unsigned short sVT[2][64 * 64];   // [buf][hd][key]   2x8KB
    __shared__ unsigned short sP [128 * 64];     // [qrow][key]      16KB
    const int t = threadIdx.x;
    const int lane = t & 63, w = t >> 6;          // w = 0..7
    const int mm = lane & 15, quad = lane >> 4;
    const int pair = blockIdx.x, bh = blockIdx.y;
    const int b = bh >> 4, hh = bh & 15;
    const size_t rowbase = (size_t)b * S_LEN;
    const int coff = hh * HD;
    const unsigned short* Vh = Vt + (size_t)bh * HD * S_LEN;

    // staging geometry: 512 lanes cover one 64x128B tile per buffer
    const int sc_ = t >> 3, sj = t & 7;
    const int sgk = sj ^ (sc_ & 7);               // XOR chunk swizzle

    u16x8 onesu;
#pragma unroll
    for (int j = 0; j < 8; ++j) onesu[j] = 0x3F80;   // bf16 1.0
    const bf16x8 ones = __builtin_bit_cast(bf16x8, onesu);

    for (int sidx = 0; sidx < 2; ++sidx) {
        const int qt = sidx ? (15 - pair) : pair;
        const int q0 = qt * 128;

        bf16x8 qf[2];
#pragma unroll
        for (int kk = 0; kk < 2; ++kk)
            qf[kk] = *(const bf16x8*)(Q + (rowbase + q0 + w * 16 + mm) * D_DIM
                                        + coff + kk * 32 + quad * 8);
        f32x4 o[4], lacc;
        lacc = (f32x4){0.f, 0.f, 0.f, 0.f};
#pragma unroll
        for (int hf = 0; hf < 4; ++hf) o[hf] = (f32x4){0.f, 0.f, 0.f, 0.f};

        const int nkt = 2 * qt + 2;
        const int qr = q0 + w * 16 + mm;          // this lane's q-row
        const int qrmax = q0 + w * 16 + 15;       // wave's max q-row
        const int m = w * 16 + mm;                // sP row

        // prologue: stage tile 0 into buf 0
        gload16(K  + (rowbase + sc_) * D_DIM + coff + sgk * 8, (void*)&sK[0][t * 8]);
        gload16(Vh + (size_t)sc_ * S_LEN + sgk * 8,            (void*)&sVT[0][t * 8]);

        for (int kt = 0; kt < nkt; ++kt) {
            const int buf = kt & 1;
            __syncthreads();   // buf's loads drained (issued a full phase ago)
            if (kt + 1 < nkt) {
                const int k1 = (kt + 1) * 64;
                gload16(K  + (rowbase + k1 + sc_) * D_DIM + coff + sgk * 8,
                        (void*)&sK[1 - buf][t * 8]);
                gload16(Vh + (size_t)sc_ * S_LEN + k1 + sgk * 8,
                        (void*)&sVT[1 - buf][t * 8]);
            }
            const int k0 = kt * 64;
            if (k0 > qrmax) continue;   // fully masked for this wave

            // S^T = K Q^T : A = K rows, B = Q rows
            f32x4 sacc[4];
#pragma unroll
            for (int kf = 0; kf < 4; ++kf) sacc[kf] = (f32x4){0.f, 0.f, 0.f, 0.f};
#pragma unroll
            for (int kk = 0; kk < 2; ++kk) {
                bf16x8 ak[4];
#pragma unroll
                for (int kf = 0; kf < 4; ++kf) {
                    int key = kf * 16 + mm;
                    int slot = (kk * 4 + quad) ^ (key & 7);
                    ak[kf] = *(const bf16x8*)&sK[buf][key * 64 + slot * 8];
                }
#pragma unroll
                for (int kf = 0; kf < 4; ++kf)
                    sacc[kf] = __builtin_amdgcn_mfma_f32_16x16x32_bf16(ak[kf], qf[kk], sacc[kf], 0, 0, 0);
            }

            // p = exp2(s), causal mask -> 0, pack to wave-private sP rows
            const bool needmask = (k0 + 63) > (q0 + w * 16);
#pragma unroll
            for (int kf = 0; kf < 4; ++kf) {
                float p[4];
#pragma unroll
                for (int r = 0; r < 4; ++r) {
                    p[r] = __builtin_amdgcn_exp2f(sacc[kf][r]);
                    if (needmask && (k0 + kf * 16 + quad * 4 + r) > qr) p[r] = 0.f;
                }
                unsigned lo = pack2(p[0], p[1]), hi = pack2(p[2], p[3]);
                int slot = (kf * 2 + (quad >> 1)) ^ (m & 7);
                *(unsigned long long*)&sP[m * 64 + slot * 8 + (quad & 1) * 4] =
                    ((unsigned long long)hi << 32) | lo;
            }

            // O += P V ; l += P * ones
#pragma unroll
            for (int kk = 0; kk < 2; ++kk) {
                bf16x8 pf, vf[4];
                {
                    int slot = (kk * 4 + quad) ^ (m & 7);
                    pf = *(const bf16x8*)&sP[m * 64 + slot * 8];
                }
#pragma unroll
                for (int hf = 0; hf < 4; ++hf) {
                    int hd = hf * 16 + mm;
                    int slot = (kk * 4 + quad) ^ (hd & 7);
                    vf[hf] = *(const bf16x8*)&sVT[buf][hd * 64 + slot * 8];
                }
                lacc = __builtin_amdgcn_mfma_f32_16x16x32_bf16(pf, ones, lacc, 0, 0, 0);
#pragma unroll
                for (int hf = 0; hf < 4; ++hf)
                    o[hf] = __builtin_amdgcn_mfma_f32_16x16x32_bf16(pf, vf[hf], o[hf], 0, 0, 0);
            }
        }
        __syncthreads();   // all compute done before next strip's prologue restages buf0

        // normalize (l already in C-layout) and store ctx
#pragma unroll
        for (int r = 0; r < 4; ++r) {
            float inv = 1.f / lacc[r];
            int row = q0 + w * 16 + quad * 4 + r;
#pragma unroll
            for (int hf = 0; hf < 4; ++hf)
                ctx[(rowbase + row) * D_DIM + coff + hf * 16 + mm] = f2bf(o[hf][r] * inv);
        }
    }
}

extern "C" void kernel_launch(void* const* d_in, const int* in_sizes, int n_in,
                              void* d_out, int out_size, void* d_ws, size_t ws_size,
                              hipStream_t stream)
{
    const float* x  = (const float*)d_in[0];
    const float* wq = (const float*)d_in[1];
    const float* wk = (const float*)d_in[2];
    const float* wv = (const float*)d_in[3];
    const float* wo = (const float*)d_in[4];

    const size_t XE = (size_t)M_ROWS * D_DIM;   // 8M elems
    const size_t WE = (size_t)D_DIM * D_DIM;    // 1M elems
    unsigned short* ws  = (unsigned short*)d_ws;
    unsigned short* xbf = ws;
    unsigned short* wt0 = xbf + XE;
    unsigned short* wt1 = wt0 + WE;
    unsigned short* wt2 = wt1 + WE;
    unsigned short* wt3 = wt2 + WE;
    unsigned short* qb  = wt3 + WE;
    unsigned short* kb  = qb + XE;
    unsigned short* vt  = kb + XE;      // V stored transposed per head
    unsigned short* cb  = vt + XE;      // ~80 MB total

    prep_k<<<dim3(4096 + 1024), 256, 0, stream>>>(x, wq, wk, wv, wo,
                                                  xbf, wt0, wt1, wt2, wt3);

    gemmqkv_k<<<dim3(3 * D_DIM / GBN, M_ROWS / GBM), 512, 0, stream>>>(xbf, wt0, qb, kb, vt);

    attn_k<<<dim3(8, BATCH * NH), 512, 0, stream>>>(qb, kb, vt, cb);

    gemmo_k<<<dim3(D_DIM / GBN, M_ROWS / GBM), 512, 0, stream>>>(cb, wt3, (float*)d_out);
}

// Round 2
// 263.180 us; speedup vs baseline: 1.0013x; 1.0013x over previous
//
#include <hip/hip_runtime.h>

#define S_LEN 2048
#define D_DIM 1024
#define NH    16
#define HD    64
#define BATCH 4
#define M_ROWS 8192

typedef __attribute__((ext_vector_type(8))) short bf16x8;   // 8 bf16 = 4 VGPR
typedef __attribute__((ext_vector_type(4))) float f32x4;
typedef __attribute__((ext_vector_type(8))) unsigned short u16x8;

__device__ __forceinline__ unsigned short f2bf(float f) {
    unsigned u = __builtin_bit_cast(unsigned, f);
    u = (u + 0x7fffu + ((u >> 16) & 1u)) >> 16;   // RNE
    return (unsigned short)u;
}
// round-half-up pack of two f32 -> packed bf16x2 (bias cancels: l from same P)
__device__ __forceinline__ unsigned pack2(float a, float b) {
    unsigned ua = __builtin_bit_cast(unsigned, a);
    unsigned ub = __builtin_bit_cast(unsigned, b);
    return ((ua + 0x8000u) >> 16) | ((ub + 0x8000u) & 0xffff0000u);
}

__device__ __forceinline__ void gload16(const void* g, void* l) {
    __builtin_amdgcn_global_load_lds((const __attribute__((address_space(1))) unsigned*)g,
                                     (__attribute__((address_space(3))) unsigned*)l,
                                     16, 0, 0);
}

// ---------------------------------------------------------------------------
// Merged prep: blocks [0,4096) cast x fp32->bf16; blocks [4096,5120) build
// W^T bf16 (wq pre-scaled by 0.125*log2(e)). One launch instead of two.
// ---------------------------------------------------------------------------
__global__ __launch_bounds__(256) void prep_k(const float* __restrict__ x,
                                              const float* __restrict__ w0, const float* __restrict__ w1,
                                              const float* __restrict__ w2, const float* __restrict__ w3,
                                              unsigned short* __restrict__ xbf,
                                              unsigned short* __restrict__ o0, unsigned short* __restrict__ o1,
                                              unsigned short* __restrict__ o2, unsigned short* __restrict__ o3) {
    __shared__ float sT[64][65];
    const int t = threadIdx.x;
    if (blockIdx.x < 4096) {
        size_t i = (size_t)blockIdx.x * 256 + t;
        const float4* xf = (const float4*)x;
        float4 a = xf[2 * i], b = xf[2 * i + 1];
        u16x8 v;
        v[0] = f2bf(a.x); v[1] = f2bf(a.y); v[2] = f2bf(a.z); v[3] = f2bf(a.w);
        v[4] = f2bf(b.x); v[5] = f2bf(b.y); v[6] = f2bf(b.z); v[7] = f2bf(b.w);
        *(u16x8*)(xbf + i * 8) = v;
        return;
    }
    const int wb = blockIdx.x - 4096;          // 0..1023
    const int z = wb >> 8;                     // weight index
    const float* w; unsigned short* o;
    switch (z) {
        case 0: w = w0; o = o0; break;
        case 1: w = w1; o = o1; break;
        case 2: w = w2; o = o2; break;
        default: w = w3; o = o3; break;
    }
    const float sc = (z == 0) ? 0.18033688011112042f : 1.0f;
    const int n0 = (wb & 15) * 64, k0 = ((wb >> 4) & 15) * 64;
    const int r = t >> 4, cq = t & 15;
#pragma unroll
    for (int it = 0; it < 4; ++it) {
        int k = r + it * 16;
        float4 v = *(const float4*)&w[(size_t)(k0 + k) * D_DIM + n0 + cq * 4];
        sT[k][cq * 4 + 0] = v.x; sT[k][cq * 4 + 1] = v.y;
        sT[k][cq * 4 + 2] = v.z; sT[k][cq * 4 + 3] = v.w;
    }
    __syncthreads();
    const int n = t >> 2, ch = t & 3;
    union { unsigned short s[8]; uint4 v; } p0, p1;
#pragma unroll
    for (int j = 0; j < 8; ++j) p0.s[j] = f2bf(sT[ch * 16 + j][n] * sc);
#pragma unroll
    for (int j = 0; j < 8; ++j) p1.s[j] = f2bf(sT[ch * 16 + 8 + j][n] * sc);
    *(uint4*)&o[(size_t)(n0 + n) * D_DIM + k0 + ch * 16]     = p0.v;
    *(uint4*)&o[(size_t)(n0 + n) * D_DIM + k0 + ch * 16 + 8] = p1.v;
}

// ---------------------------------------------------------------------------
// 256x256 fine-phase GEMM core (T3+T4+T5 per m201/m218 evidence).
// BK=32, 8 waves (wm in {0,1} x wn in {0..3}); per-wave output 128x64 split as
// qm in {0,1} selecting A-half (rows qm*128 + wm*64 + mf*16), cols wn*64+nf*16.
// LDS: 4-slot ring x (A 256x32 + B 256x32) = 128KB. Stage tile T+3 during
// tile T (slot freed at tile T-1's closing barrier). One counted vmcnt(8)
// per tile (2 tiles = 8 gload-instr in flight); epilogue drains 4 -> 0.
// Per phase: {4 or 8 ds_read_b128} + {2 global_load_lds} + barrier +
// lgkmcnt(0) + setprio(1) + 16 MFMA + setprio(0) [+vmcnt] + barrier.
// Chunk swizzle c ^ ((row>>1)&3): each 16-lane group covers all 8 16B slots
// per 128B bank window -> 2-way (free) on every ds_read_b128.
// ---------------------------------------------------------------------------
static constexpr int BM = 256, BN = 256, BK = 32;

#define TILE_STEP(T_, WN_, ST_)                                                         \
{                                                                                       \
    const int slot_ = (T_) & 3;                                                         \
    const unsigned so_ = (unsigned)slot_ * 8192u;                                       \
    bf16x8 af_[4], bv_[4];                                                              \
    _Pragma("unroll")                                                                   \
    for (int nf = 0; nf < 4; ++nf)                                                      \
        bv_[nf] = *(const bf16x8*)&sB[so_ + bh * 4096 + (bl + nf * 16) * 32 + xs * 8];  \
    _Pragma("unroll")                                                                   \
    for (int mf = 0; mf < 4; ++mf)                                                      \
        af_[mf] = *(const bf16x8*)&sA[so_ + (al + mf * 16) * 32 + xs * 8];              \
    if (ST_) {                                                                          \
        const int ko_ = ((T_) + 3) * 32;                                                \
        const unsigned wd_ = (unsigned)(((T_) + 3) & 3) * 8192u;                        \
        gload16(a0 + ko_, dA + wd_);                                                    \
        gload16(b0 + ko_, dB + wd_);                                                    \
    }                                                                                   \
    __builtin_amdgcn_s_barrier();                                                       \
    asm volatile("s_waitcnt lgkmcnt(0)" ::: "memory");                                  \
    __builtin_amdgcn_s_setprio(1);                                                      \
    _Pragma("unroll")                                                                   \
    for (int mf = 0; mf < 4; ++mf)                                                      \
        _Pragma("unroll")                                                               \
        for (int nf = 0; nf < 4; ++nf)                                                  \
            acc[0][mf][nf] = __builtin_amdgcn_mfma_f32_16x16x32_bf16(af_[mf], bv_[nf], acc[0][mf][nf], 0, 0, 0); \
    __builtin_amdgcn_s_setprio(0);                                                      \
    __builtin_amdgcn_s_barrier();                                                       \
    _Pragma("unroll")                                                                   \
    for (int mf = 0; mf < 4; ++mf)                                                      \
        af_[mf] = *(const bf16x8*)&sA[so_ + 4096 + (al + mf * 16) * 32 + xs * 8];       \
    if (ST_) {                                                                          \
        const int ko_ = ((T_) + 3) * 32;                                                \
        const unsigned wd_ = (unsigned)(((T_) + 3) & 3) * 8192u;                        \
        gload16(a1 + ko_, dA + wd_ + 4096);                                             \
        gload16(b1 + ko_, dB + wd_ + 4096);                                             \
    }                                                                                   \
    __builtin_amdgcn_s_barrier();                                                       \
    asm volatile("s_waitcnt lgkmcnt(0)" ::: "memory");                                  \
    __builtin_amdgcn_s_setprio(1);                                                      \
    _Pragma("unroll")                                                                   \
    for (int mf = 0; mf < 4; ++mf)                                                      \
        _Pragma("unroll")                                                               \
        for (int nf = 0; nf < 4; ++nf)                                                  \
            acc[1][mf][nf] = __builtin_amdgcn_mfma_f32_16x16x32_bf16(af_[mf], bv_[nf], acc[1][mf][nf], 0, 0, 0); \
    __builtin_amdgcn_s_setprio(0);                                                      \
    if ((WN_) == 8)      asm volatile("s_waitcnt vmcnt(8)" ::: "memory");               \
    else if ((WN_) == 4) asm volatile("s_waitcnt vmcnt(4)" ::: "memory");               \
    else if ((WN_) == 0) asm volatile("s_waitcnt vmcnt(0)" ::: "memory");               \
    __builtin_amdgcn_s_barrier();                                                       \
}

__device__ __forceinline__ void gemm256(const unsigned short* __restrict__ A,
                                        const unsigned short* __restrict__ Bt,
                                        unsigned short* sA, unsigned short* sB,
                                        int m0, int n0, int t,
                                        f32x4 (&acc)[2][4][4])
{
    const int lane = t & 63, wid = t >> 6;
    const int mm = lane & 15, quad = lane >> 4;
    const int wm = wid >> 2, wn = wid & 3;

    // staging: thread t covers (row sr, 16B-chunk sj) of a 128x32 half;
    // pre-swizzled global chunk g = sj ^ ((sr>>1)&3)  (inverse == forward)
    const int sr = t >> 2;
    const int sg = (t & 3) ^ ((sr >> 1) & 3);
    const unsigned short* a0 = A  + (size_t)(m0 + sr) * D_DIM + sg * 8;
    const unsigned short* a1 = a0 + 128 * D_DIM;
    const unsigned short* b0 = Bt + (size_t)(n0 + sr) * D_DIM + sg * 8;
    const unsigned short* b1 = b0 + 128 * D_DIM;
    unsigned short* dA = sA + t * 8;
    unsigned short* dB = sB + t * 8;

    // read-side geometry
    const int al = wm * 64 + mm;         // + mf*16 : local row in A-half
    const int bl = (wn & 1) * 64 + mm;   // + nf*16 : local row in B-half
    const int bh = wn >> 1;              // B-half fixed per wave
    const int xs = quad ^ ((mm >> 1) & 3);   // swizzled chunk for reads

    // prologue: tiles 0..2 (12 gload-instructions, FIFO per-tile groups of 4)
#pragma unroll
    for (int pt = 0; pt < 3; ++pt) {
        const int ko = pt * 32;
        const unsigned wd = (unsigned)pt * 8192u;
        gload16(a0 + ko, dA + wd);
        gload16(b0 + ko, dB + wd);
        gload16(a1 + ko, dA + wd + 4096);
        gload16(b1 + ko, dB + wd + 4096);
    }
    asm volatile("s_waitcnt vmcnt(8)" ::: "memory");   // tile 0 landed; 1,2 in flight
    __builtin_amdgcn_s_barrier();

    for (int T = 0; T < 28; ++T) TILE_STEP(T, 8, true);
    TILE_STEP(28, 8, true);     // stages tile 31 (last)
    TILE_STEP(29, 4, false);    // confirm tile 30, leave 31 in flight
    TILE_STEP(30, 0, false);    // confirm tile 31
    TILE_STEP(31, -1, false);
}

// ---------------------------------------------------------------------------
// Fused QKV GEMM, 256x256 tiles. N covers [Wq|Wk|Wv] (N=3072; 256-tiles never
// cross a weight boundary). Grid 384 blocks, 1/CU; bijective XCD swizzle
// chunks 4 m-tiles x 12 n-tiles per XCD (A-panels 2MB -> L2-resident).
// ---------------------------------------------------------------------------
__global__ __launch_bounds__(512, 2) void gemmqkv_k(const unsigned short* __restrict__ A,
                                                    const unsigned short* __restrict__ Bt,
                                                    unsigned short* __restrict__ qb,
                                                    unsigned short* __restrict__ kb,
                                                    unsigned short* __restrict__ vt)
{
    __shared__ unsigned short sA[4 * 2 * 128 * 32];   // 64KB
    __shared__ unsigned short sB[4 * 2 * 128 * 32];   // 64KB
    const int t = threadIdx.x;
    const int bid = blockIdx.x;                       // 384 = 8*48
    const int wg = (bid & 7) * 48 + (bid >> 3);       // bijective XCD chunking
    const int mt = wg / 12, nt = wg % 12;
    const int m0 = mt * BM, n0 = nt * BN;

    f32x4 acc[2][4][4];
#pragma unroll
    for (int q = 0; q < 2; ++q)
#pragma unroll
        for (int i = 0; i < 4; ++i)
#pragma unroll
            for (int j = 0; j < 4; ++j) acc[q][i][j] = (f32x4){0.f, 0.f, 0.f, 0.f};

    gemm256(A, Bt, sA, sB, m0, n0, t, acc);

    const int lane = t & 63, wid = t >> 6;
    const int mm = lane & 15, quad = lane >> 4;
    const int wm = wid >> 2, wn = wid & 3;
    const int widx = n0 >> 10, nl0 = n0 & 1023;

    if (widx == 2) {
        // V: write transposed per head
#pragma unroll
        for (int qm = 0; qm < 2; ++qm)
#pragma unroll
        for (int mi = 0; mi < 4; ++mi) {
            int rglob = m0 + qm * 128 + wm * 64 + mi * 16 + quad * 4;
            int bb = rglob >> 11, ss = rglob & (S_LEN - 1);
#pragma unroll
            for (int ni = 0; ni < 4; ++ni) {
                int c = nl0 + wn * 64 + ni * 16 + mm;
                int h = c >> 6, hd = c & 63;
                union { unsigned short s[4]; unsigned long long ll; } pk;
#pragma unroll
                for (int r = 0; r < 4; ++r) pk.s[r] = f2bf(acc[qm][mi][ni][r]);
                *(unsigned long long*)&vt[((size_t)(bb * NH + h) * HD + hd) * S_LEN + ss] = pk.ll;
            }
        }
    } else {
        unsigned short* outp = widx ? kb : qb;
#pragma unroll
        for (int qm = 0; qm < 2; ++qm)
#pragma unroll
        for (int mi = 0; mi < 4; ++mi)
#pragma unroll
            for (int ni = 0; ni < 4; ++ni)
#pragma unroll
                for (int r = 0; r < 4; ++r)
                    outp[(size_t)(m0 + qm * 128 + wm * 64 + mi * 16 + quad * 4 + r) * D_DIM +
                         nl0 + wn * 64 + ni * 16 + mm] = f2bf(acc[qm][mi][ni][r]);
    }
}

// ---------------------------------------------------------------------------
// Output GEMM: out_fp32 = ctx_bf16 * WoT^T.  Grid 128 blocks (32m x 4n),
// XCD chunks 4m x 4n (A 2MB + B 2MB = L2-fit per XCD).
// ---------------------------------------------------------------------------
__global__ __launch_bounds__(512, 2) void gemmo_k(const unsigned short* __restrict__ A,
                                                  const unsigned short* __restrict__ Bt,
                                                  float* __restrict__ C)
{
    __shared__ unsigned short sA[4 * 2 * 128 * 32];
    __shared__ unsigned short sB[4 * 2 * 128 * 32];
    const int t = threadIdx.x;
    const int bid = blockIdx.x;                       // 128 = 8*16
    const int wg = (bid & 7) * 16 + (bid >> 3);
    const int mt = wg >> 2, nt = wg & 3;
    const int m0 = mt * BM, n0 = nt * BN;

    f32x4 acc[2][4][4];
#pragma unroll
    for (int q = 0; q < 2; ++q)
#pragma unroll
        for (int i = 0; i < 4; ++i)
#pragma unroll
            for (int j = 0; j < 4; ++j) acc[q][i][j] = (f32x4){0.f, 0.f, 0.f, 0.f};

    gemm256(A, Bt, sA, sB, m0, n0, t, acc);

    const int lane = t & 63, wid = t >> 6;
    const int mm = lane & 15, quad = lane >> 4;
    const int wm = wid >> 2, wn = wid & 3;

#pragma unroll
    for (int qm = 0; qm < 2; ++qm)
#pragma unroll
    for (int mi = 0; mi < 4; ++mi)
#pragma unroll
        for (int ni = 0; ni < 4; ++ni)
#pragma unroll
            for (int r = 0; r < 4; ++r)
                C[(size_t)(m0 + qm * 128 + wm * 64 + mi * 16 + quad * 4 + r) * D_DIM +
                  n0 + wn * 64 + ni * 16 + mm] = acc[qm][mi][ni][r];
}

// ---------------------------------------------------------------------------
// Fused causal flash attention (round-4 verified config: 74.5 us).
// 512 threads (8 waves), 16 q-rows/wave, block covers strips {qt, 15-qt}
// (uniform 34 k-tiles of 64 keys). K/V^T double-buffered, prefetch issued
// right after the per-tile barrier (long compute phase hides the drain).
// l computed via MFMA against all-ones B; sP rows are wave-private.
// ---------------------------------------------------------------------------
__global__ __launch_bounds__(512, 4) void attn_k(const unsigned short* __restrict__ Q,
                                                 const unsigned short* __restrict__ K,
                                                 const unsigned short* __restrict__ Vt,
                                                 unsigned short* __restrict__ ctx)
{
    __shared__ unsigned short sK [2][64 * 64];   // [buf][key][hd]   2x8KB
    __shared__ unsigned short sVT[2][64 * 64];   // [buf][hd][key]   2x8KB
    __shared__ unsigned short sP [128 * 64];     // [qrow][key]      16KB
    const int t = threadIdx.x;
    const int lane = t & 63, w = t >> 6;          // w = 0..7
    const int mm = lane & 15, quad = lane >> 4;
    const int pair = blockIdx.x, bh = blockIdx.y;
    const int b = bh >> 4, hh = bh & 15;
    const size_t rowbase = (size_t)b * S_LEN;
    const int coff = hh * HD;
    const unsigned short* Vh = Vt + (size_t)bh * HD * S_LEN;

    // staging geometry: 512 lanes cover one 64x128B tile per buffer
    const int sc_ = t >> 3, sj = t & 7;
    const int sgk = sj ^ (sc_ & 7);               // XOR chunk swizzle

    u16x8 onesu;
#pragma unroll
    for (int j = 0; j < 8; ++j) onesu[j] = 0x3F80;   // bf16 1.0
    const bf16x8 ones = __builtin_bit_cast(bf16x8, onesu);

    for (int sidx = 0; sidx < 2; ++sidx) {
        const int qt = sidx ? (15 - pair) : pair;
        const int q0 = qt * 128;

        bf16x8 qf[2];
#pragma unroll
        for (int kk = 0; kk < 2; ++kk)
            qf[kk] = *(const bf16x8*)(Q + (rowbase + q0 + w * 16 + mm) * D_DIM
                                        + coff + kk * 32 + quad * 8);
        f32x4 o[4], lacc;
        lacc = (f32x4){0.f, 0.f, 0.f, 0.f};
#pragma unroll
        for (int hf = 0; hf < 4; ++hf) o[hf] = (f32x4){0.f, 0.f, 0.f, 0.f};

        const int nkt = 2 * qt + 2;
        const int qr = q0 + w * 16 + mm;          // this lane's q-row
        const int qrmax = q0 + w * 16 + 15;       // wave's max q-row
        const int m = w * 16 + mm;                // sP row

        // prologue: stage tile 0 into buf 0
        gload16(K  + (rowbase + sc_) * D_DIM + coff + sgk * 8, (void*)&sK[0][t * 8]);
        gload16(Vh + (size_t)sc_ * S_LEN + sgk * 8,            (void*)&sVT[0][t * 8]);

        for (int kt = 0; kt < nkt; ++kt) {
            const int buf = kt & 1;
            __syncthreads();   // buf's loads drained (issued a full phase ago)
            if (kt + 1 < nkt) {
                const int k1 = (kt + 1) * 64;
                gload16(K  + (rowbase + k1 + sc_) * D_DIM + coff + sgk * 8,
                        (void*)&sK[1 - buf][t * 8]);
                gload16(Vh + (size_t)sc_ * S_LEN + k1 + sgk * 8,
                        (void*)&sVT[1 - buf][t * 8]);
            }
            const int k0 = kt * 64;
            if (k0 > qrmax) continue;   // fully masked for this wave

            // S^T = K Q^T : A = K rows, B = Q rows
            f32x4 sacc[4];
#pragma unroll
            for (int kf = 0; kf < 4; ++kf) sacc[kf] = (f32x4){0.f, 0.f, 0.f, 0.f};
#pragma unroll
            for (int kk = 0; kk < 2; ++kk) {
                bf16x8 ak[4];
#pragma unroll
                for (int kf = 0; kf < 4; ++kf) {
                    int key = kf * 16 + mm;
                    int slot = (kk * 4 + quad) ^ (key & 7);
                    ak[kf] = *(const bf16x8*)&sK[buf][key * 64 + slot * 8];
                }
#pragma unroll
                for (int kf = 0; kf < 4; ++kf)
                    sacc[kf] = __builtin_amdgcn_mfma_f32_16x16x32_bf16(ak[kf], qf[kk], sacc[kf], 0, 0, 0);
            }

            // p = exp2(s), causal mask -> 0, pack to wave-private sP rows
            const bool needmask = (k0 + 63) > (q0 + w * 16);
#pragma unroll
            for (int kf = 0; kf < 4; ++kf) {
                float p[4];
#pragma unroll
                for (int r = 0; r < 4; ++r) {
                    p[r] = __builtin_amdgcn_exp2f(sacc[kf][r]);
                    if (needmask && (k0 + kf * 16 + quad * 4 + r) > qr) p[r] = 0.f;
                }
                unsigned lo = pack2(p[0], p[1]), hi = pack2(p[2], p[3]);
                int slot = (kf * 2 + (quad >> 1)) ^ (m & 7);
                *(unsigned long long*)&sP[m * 64 + slot * 8 + (quad & 1) * 4] =
                    ((unsigned long long)hi << 32) | lo;
            }

            // O += P V ; l += P * ones
#pragma unroll
            for (int kk = 0; kk < 2; ++kk) {
                bf16x8 pf, vf[4];
                {
                    int slot = (kk * 4 + quad) ^ (m & 7);
                    pf = *(const bf16x8*)&sP[m * 64 + slot * 8];
                }
#pragma unroll
                for (int hf = 0; hf < 4; ++hf) {
                    int hd = hf * 16 + mm;
                    int slot = (kk * 4 + quad) ^ (hd & 7);
                    vf[hf] = *(const bf16x8*)&sVT[buf][hd * 64 + slot * 8];
                }
                lacc = __builtin_amdgcn_mfma_f32_16x16x32_bf16(pf, ones, lacc, 0, 0, 0);
#pragma unroll
                for (int hf = 0; hf < 4; ++hf)
                    o[hf] = __builtin_amdgcn_mfma_f32_16x16x32_bf16(pf, vf[hf], o[hf], 0, 0, 0);
            }
        }
        __syncthreads();   // all compute done before next strip's prologue restages buf0

        // normalize (l already in C-layout) and store ctx
#pragma unroll
        for (int r = 0; r < 4; ++r) {
            float inv = 1.f / lacc[r];
            int row = q0 + w * 16 + quad * 4 + r;
#pragma unroll
            for (int hf = 0; hf < 4; ++hf)
                ctx[(rowbase + row) * D_DIM + coff + hf * 16 + mm] = f2bf(o[hf][r] * inv);
        }
    }
}

extern "C" void kernel_launch(void* const* d_in, const int* in_sizes, int n_in,
                              void* d_out, int out_size, void* d_ws, size_t ws_size,
                              hipStream_t stream)
{
    const float* x  = (const float*)d_in[0];
    const float* wq = (const float*)d_in[1];
    const float* wk = (const float*)d_in[2];
    const float* wv = (const float*)d_in[3];
    const float* wo = (const float*)d_in[4];

    const size_t XE = (size_t)M_ROWS * D_DIM;   // 8M elems
    const size_t WE = (size_t)D_DIM * D_DIM;    // 1M elems
    unsigned short* ws  = (unsigned short*)d_ws;
    unsigned short* xbf = ws;
    unsigned short* wt0 = xbf + XE;
    unsigned short* wt1 = wt0 + WE;
    unsigned short* wt2 = wt1 + WE;
    unsigned short* wt3 = wt2 + WE;
    unsigned short* qb  = wt3 + WE;
    unsigned short* kb  = qb + XE;
    unsigned short* vt  = kb + XE;      // V stored transposed per head
    unsigned short* cb  = vt + XE;      // ~80 MB total

    prep_k<<<dim3(4096 + 1024), 256, 0, stream>>>(x, wq, wk, wv, wo,
                                                  xbf, wt0, wt1, wt2, wt3);

    gemmqkv_k<<<dim3(384), 512, 0, stream>>>(xbf, wt0, qb, kb, vt);

    attn_k<<<dim3(8, BATCH * NH), 512, 0, stream>>>(qb, kb, vt, cb);

    gemmo_k<<<dim3(128), 512, 0, stream>>>(cb, wt3, (float*)d_out);
}

// Round 3
// 252.250 us; speedup vs baseline: 1.0447x; 1.0433x over previous
//
#include <hip/hip_runtime.h>

#define S_LEN 2048
#define D_DIM 1024
#define NH    16
#define HD    64
#define BATCH 4
#define M_ROWS 8192

typedef __attribute__((ext_vector_type(8))) short bf16x8;   // 8 bf16 = 4 VGPR
typedef __attribute__((ext_vector_type(4))) float f32x4;
typedef __attribute__((ext_vector_type(8))) unsigned short u16x8;

__device__ __forceinline__ unsigned short f2bf(float f) {
    unsigned u = __builtin_bit_cast(unsigned, f);
    u = (u + 0x7fffu + ((u >> 16) & 1u)) >> 16;   // RNE
    return (unsigned short)u;
}
// round-half-up pack of two f32 -> packed bf16x2 (bias cancels: l from same P)
__device__ __forceinline__ unsigned pack2(float a, float b) {
    unsigned ua = __builtin_bit_cast(unsigned, a);
    unsigned ub = __builtin_bit_cast(unsigned, b);
    return ((ua + 0x8000u) >> 16) | ((ub + 0x8000u) & 0xffff0000u);
}

__device__ __forceinline__ void gload16(const void* g, void* l) {
    __builtin_amdgcn_global_load_lds((const __attribute__((address_space(1))) unsigned*)g,
                                     (__attribute__((address_space(3))) unsigned*)l,
                                     16, 0, 0);
}

template<int N> __device__ __forceinline__ void vmwait() {
    if constexpr (N == 0)      asm volatile("s_waitcnt vmcnt(0)" ::: "memory");
    else if constexpr (N == 3) asm volatile("s_waitcnt vmcnt(3)" ::: "memory");
    else if constexpr (N == 4) asm volatile("s_waitcnt vmcnt(4)" ::: "memory");
    else if constexpr (N == 6) asm volatile("s_waitcnt vmcnt(6)" ::: "memory");
    else if constexpr (N == 8) asm volatile("s_waitcnt vmcnt(8)" ::: "memory");
    // N < 0: no wait
}

// ---------------------------------------------------------------------------
// Merged prep: blocks [0,4096) cast x fp32->bf16; blocks [4096,5120) build
// W^T bf16 (wq pre-scaled by 0.125*log2(e)). One launch instead of two.
// ---------------------------------------------------------------------------
__global__ __launch_bounds__(256) void prep_k(const float* __restrict__ x,
                                              const float* __restrict__ w0, const float* __restrict__ w1,
                                              const float* __restrict__ w2, const float* __restrict__ w3,
                                              unsigned short* __restrict__ xbf,
                                              unsigned short* __restrict__ o0, unsigned short* __restrict__ o1,
                                              unsigned short* __restrict__ o2, unsigned short* __restrict__ o3) {
    __shared__ float sT[64][65];
    const int t = threadIdx.x;
    if (blockIdx.x < 4096) {
        size_t i = (size_t)blockIdx.x * 256 + t;
        const float4* xf = (const float4*)x;
        float4 a = xf[2 * i], b = xf[2 * i + 1];
        u16x8 v;
        v[0] = f2bf(a.x); v[1] = f2bf(a.y); v[2] = f2bf(a.z); v[3] = f2bf(a.w);
        v[4] = f2bf(b.x); v[5] = f2bf(b.y); v[6] = f2bf(b.z); v[7] = f2bf(b.w);
        *(u16x8*)(xbf + i * 8) = v;
        return;
    }
    const int wb = blockIdx.x - 4096;          // 0..1023
    const int z = wb >> 8;                     // weight index
    const float* w; unsigned short* o;
    switch (z) {
        case 0: w = w0; o = o0; break;
        case 1: w = w1; o = o1; break;
        case 2: w = w2; o = o2; break;
        default: w = w3; o = o3; break;
    }
    const float sc = (z == 0) ? 0.18033688011112042f : 1.0f;
    const int n0 = (wb & 15) * 64, k0 = ((wb >> 4) & 15) * 64;
    const int r = t >> 4, cq = t & 15;
#pragma unroll
    for (int it = 0; it < 4; ++it) {
        int k = r + it * 16;
        float4 v = *(const float4*)&w[(size_t)(k0 + k) * D_DIM + n0 + cq * 4];
        sT[k][cq * 4 + 0] = v.x; sT[k][cq * 4 + 1] = v.y;
        sT[k][cq * 4 + 2] = v.z; sT[k][cq * 4 + 3] = v.w;
    }
    __syncthreads();
    const int n = t >> 2, ch = t & 3;
    union { unsigned short s[8]; uint4 v; } p0, p1;
#pragma unroll
    for (int j = 0; j < 8; ++j) p0.s[j] = f2bf(sT[ch * 16 + j][n] * sc);
#pragma unroll
    for (int j = 0; j < 8; ++j) p1.s[j] = f2bf(sT[ch * 16 + 8 + j][n] * sc);
    *(uint4*)&o[(size_t)(n0 + n) * D_DIM + k0 + ch * 16]     = p0.v;
    *(uint4*)&o[(size_t)(n0 + n) * D_DIM + k0 + ch * 16 + 8] = p1.v;
}

// ---------------------------------------------------------------------------
// Fine-phase GEMM core, BM=128, BN = NFRAG*64, BK=32. 8 waves (2M x 4N):
// per-wave output 64 x NFRAG*16, acc[4][NFRAG]. 4-slot LDS ring; stage tile
// T+3 while computing T (slot (T+3)&3 == (T-1)&3, freed at T-1's barrier).
// ONE barrier per tile: {NGLD gloads (T+3) | 4+NFRAG ds_read_b128 (T) |
// lgkmcnt(0) | setprio(1) 4*NFRAG MFMA setprio(0) | vmcnt(2*NGLD) | barrier}.
// Counted vmcnt keeps 2 tiles in flight across barriers (T4); drains only in
// the 3-step epilogue. XOR chunk swizzle (write side pre-swizzles the global
// source; read side xs = quad ^ ((mm>>1)&3)) -> measured 0 bank conflicts.
// ---------------------------------------------------------------------------
template<int NFRAG, int NGLD>
__device__ __forceinline__ void gemm_core(const unsigned short* __restrict__ A,
                                          const unsigned short* __restrict__ Bt,
                                          unsigned short* __restrict__ sA,
                                          unsigned short* __restrict__ sB,
                                          int m0, int n0, int t,
                                          f32x4 (&acc)[4][NFRAG])
{
    constexpr int BSLOT = (NGLD - 1) * 4096;      // B elems per ring slot
    const int lane = t & 63, wid = t >> 6;
    const int mm = lane & 15, quad = lane >> 4;
    const int wm = wid >> 2, wn = wid & 3;

    // staging: thread t covers (row t>>2, 16B chunk t&3) of each 128x32 pass;
    // pre-swizzled global chunk g = j ^ ((row>>1)&3) (involution)
    const int sr = t >> 2;
    const int sg = (t & 3) ^ ((sr >> 1) & 3);
    const unsigned short* asrc  = A  + (size_t)(m0 + sr) * D_DIM + sg * 8;
    const unsigned short* bsrc0 = Bt + (size_t)(n0 + sr) * D_DIM + sg * 8;
    unsigned short* dA = sA + t * 8;
    unsigned short* dB = sB + t * 8;

    // read-side geometry (row-XOR folds to a per-thread constant: all frag
    // row offsets are multiples of 16, so ((row>>1)&3) == ((mm>>1)&3))
    const int al = wm * 64 + mm;
    const int bl = wn * (NFRAG * 16) + mm;
    const int xs = quad ^ ((mm >> 1) & 3);

    // prologue: tiles 0..2 staged (3*NGLD gloads); wait tile 0, keep 1,2 in flight
#pragma unroll
    for (int pt = 0; pt < 3; ++pt) {
        const int ko = pt * 32;
        gload16(asrc + ko, dA + pt * 4096);
#pragma unroll
        for (int p = 0; p < NGLD - 1; ++p)
            gload16(bsrc0 + (size_t)p * 128 * D_DIM + ko, dB + pt * BSLOT + p * 4096);
    }
    vmwait<2 * NGLD>();
    __builtin_amdgcn_s_barrier();

#define GTILE(T_, W_, ST_)                                                                 \
{                                                                                          \
    const unsigned soA_ = (unsigned)((T_) & 3) * 4096u;                                    \
    const unsigned soB_ = (unsigned)((T_) & 3) * (unsigned)BSLOT;                          \
    if (ST_) {                                                                             \
        const int ko_ = ((T_) + 3) * 32;                                                   \
        const unsigned wA_ = (unsigned)(((T_) + 3) & 3) * 4096u;                           \
        const unsigned wB_ = (unsigned)(((T_) + 3) & 3) * (unsigned)BSLOT;                 \
        gload16(asrc + ko_, dA + wA_);                                                     \
        _Pragma("unroll")                                                                  \
        for (int p_ = 0; p_ < NGLD - 1; ++p_)                                              \
            gload16(bsrc0 + (size_t)p_ * 128 * D_DIM + ko_, dB + wB_ + p_ * 4096);         \
    }                                                                                      \
    bf16x8 af_[4], bv_[NFRAG];                                                             \
    _Pragma("unroll")                                                                      \
    for (int nf = 0; nf < NFRAG; ++nf)                                                     \
        bv_[nf] = *(const bf16x8*)&sB[soB_ + (unsigned)(bl + nf * 16) * 32 + xs * 8];      \
    _Pragma("unroll")                                                                      \
    for (int mf = 0; mf < 4; ++mf)                                                         \
        af_[mf] = *(const bf16x8*)&sA[soA_ + (unsigned)(al + mf * 16) * 32 + xs * 8];      \
    asm volatile("s_waitcnt lgkmcnt(0)" ::: "memory");                                     \
    __builtin_amdgcn_s_setprio(1);                                                         \
    _Pragma("unroll")                                                                      \
    for (int mf = 0; mf < 4; ++mf)                                                         \
        _Pragma("unroll")                                                                  \
        for (int nf = 0; nf < NFRAG; ++nf)                                                 \
            acc[mf][nf] = __builtin_amdgcn_mfma_f32_16x16x32_bf16(af_[mf], bv_[nf], acc[mf][nf], 0, 0, 0); \
    __builtin_amdgcn_s_setprio(0);                                                         \
    vmwait<(W_)>();                                                                        \
    __builtin_amdgcn_s_barrier();                                                          \
}

#pragma unroll 4
    for (int T = 0; T < 28; ++T) GTILE(T, 2 * NGLD, true);
    GTILE(28, 2 * NGLD, true);     // stages tile 31 (last)
    GTILE(29, NGLD, false);        // drain to 1 tile in flight
    GTILE(30, 0, false);           // drain fully
    GTILE(31, -1, false);
#undef GTILE
}

// ---------------------------------------------------------------------------
// Fused QKV GEMM: BM=128, BN=384, grid 64m x 8n = 512 blocks = 2.0 exact
// rounds at 1 block/CU. B^T = [Wq^T|Wk^T|Wv^T] contiguous (3072 rows); a
// 384-wide tile may span weight boundaries -- epilogue routes per 16-wide
// fragment (widx wave-uniform since fragments are 16-aligned). XCD chunking:
// 8 m-tiles x all n per XCD -> A panel 2MB L2-resident.
// ---------------------------------------------------------------------------
__global__ __launch_bounds__(512, 2) void gemmqkv_k(const unsigned short* __restrict__ A,
                                                    const unsigned short* __restrict__ Bt,
                                                    unsigned short* __restrict__ qb,
                                                    unsigned short* __restrict__ kb,
                                                    unsigned short* __restrict__ vt)
{
    __shared__ unsigned short sA[4 * 4096];        // 32KB
    __shared__ unsigned short sB[4 * 3 * 4096];    // 96KB
    const int t = threadIdx.x;
    const int bid = blockIdx.x;                    // 512 = 8 XCD * 64
    const int wg = (bid & 7) * 64 + (bid >> 3);
    const int mt = wg >> 3, nt = wg & 7;
    const int m0 = mt * 128, n0 = nt * 384;

    f32x4 acc[4][6];
#pragma unroll
    for (int i = 0; i < 4; ++i)
#pragma unroll
        for (int j = 0; j < 6; ++j) acc[i][j] = (f32x4){0.f, 0.f, 0.f, 0.f};

    gemm_core<6, 4>(A, Bt, sA, sB, m0, n0, t, acc);

    const int lane = t & 63, wid = t >> 6;
    const int mm = lane & 15, quad = lane >> 4;
    const int wm = wid >> 2, wn = wid & 3;

#pragma unroll
    for (int nf = 0; nf < 6; ++nf) {
        const int c0 = n0 + wn * 96 + nf * 16;     // 16-aligned -> widx uniform
        const int widx = c0 >> 10, nl0 = c0 & 1023;
        if (widx == 2) {
            // V: write transposed per head (head-crossing impossible: c0&63 <= 48)
            const int h = nl0 >> 6, hd = (nl0 & 63) + mm;
#pragma unroll
            for (int mf = 0; mf < 4; ++mf) {
                int rglob = m0 + wm * 64 + mf * 16 + quad * 4;
                int bb = rglob >> 11, ss = rglob & (S_LEN - 1);
                union { unsigned short s[4]; unsigned long long ll; } pk;
#pragma unroll
                for (int r = 0; r < 4; ++r) pk.s[r] = f2bf(acc[mf][nf][r]);
                *(unsigned long long*)&vt[((size_t)(bb * NH + h) * HD + hd) * S_LEN + ss] = pk.ll;
            }
        } else {
            unsigned short* outp = widx ? kb : qb;
#pragma unroll
            for (int mf = 0; mf < 4; ++mf)
#pragma unroll
                for (int r = 0; r < 4; ++r)
                    outp[(size_t)(m0 + wm * 64 + mf * 16 + quad * 4 + r) * D_DIM +
                         nl0 + mm] = f2bf(acc[mf][nf][r]);
        }
    }
}

// ---------------------------------------------------------------------------
// Output GEMM: out_fp32 = ctx_bf16 * WoT^T. BM=128, BN=256, grid 64m x 4n =
// 256 blocks = 1.0 exact round (was 128 blocks = half the CUs idle!).
// XCD chunking 8m x 4n: A 2MB + B 2MB both L2-resident per XCD.
// ---------------------------------------------------------------------------
__global__ __launch_bounds__(512, 2) void gemmo_k(const unsigned short* __restrict__ A,
                                                  const unsigned short* __restrict__ Bt,
                                                  float* __restrict__ C)
{
    __shared__ unsigned short sA[4 * 4096];        // 32KB
    __shared__ unsigned short sB[4 * 2 * 4096];    // 64KB
    const int t = threadIdx.x;
    const int bid = blockIdx.x;                    // 256 = 8 XCD * 32
    const int wg = (bid & 7) * 32 + (bid >> 3);
    const int mt = wg >> 2, nt = wg & 3;
    const int m0 = mt * 128, n0 = nt * 256;

    f32x4 acc[4][4];
#pragma unroll
    for (int i = 0; i < 4; ++i)
#pragma unroll
        for (int j = 0; j < 4; ++j) acc[i][j] = (f32x4){0.f, 0.f, 0.f, 0.f};

    gemm_core<4, 3>(A, Bt, sA, sB, m0, n0, t, acc);

    const int lane = t & 63, wid = t >> 6;
    const int mm = lane & 15, quad = lane >> 4;
    const int wm = wid >> 2, wn = wid & 3;

#pragma unroll
    for (int mf = 0; mf < 4; ++mf)
#pragma unroll
        for (int nf = 0; nf < 4; ++nf)
#pragma unroll
            for (int r = 0; r < 4; ++r)
                C[(size_t)(m0 + wm * 64 + mf * 16 + quad * 4 + r) * D_DIM +
                  n0 + wn * 64 + nf * 16 + mm] = acc[mf][nf][r];
}

// ---------------------------------------------------------------------------
// Fused causal flash attention (verified config: 74.5 us).
// 512 threads (8 waves), 16 q-rows/wave, block covers strips {qt, 15-qt}
// (uniform 34 k-tiles of 64 keys). K/V^T double-buffered, prefetch issued
// right after the per-tile barrier (long compute phase hides the drain).
// l computed via MFMA against all-ones B; sP rows are wave-private.
// ---------------------------------------------------------------------------
__global__ __launch_bounds__(512, 4) void attn_k(const unsigned short* __restrict__ Q,
                                                 const unsigned short* __restrict__ K,
                                                 const unsigned short* __restrict__ Vt,
                                                 unsigned short* __restrict__ ctx)
{
    __shared__ unsigned short sK [2][64 * 64];   // [buf][key][hd]   2x8KB
    __shared__ unsigned short sVT[2][64 * 64];   // [buf][hd][key]   2x8KB
    __shared__ unsigned short sP [128 * 64];     // [qrow][key]      16KB
    const int t = threadIdx.x;
    const int lane = t & 63, w = t >> 6;          // w = 0..7
    const int mm = lane & 15, quad = lane >> 4;
    const int pair = blockIdx.x, bh = blockIdx.y;
    const int b = bh >> 4, hh = bh & 15;
    const size_t rowbase = (size_t)b * S_LEN;
    const int coff = hh * HD;
    const unsigned short* Vh = Vt + (size_t)bh * HD * S_LEN;

    // staging geometry: 512 lanes cover one 64x128B tile per buffer
    const int sc_ = t >> 3, sj = t & 7;
    const int sgk = sj ^ (sc_ & 7);               // XOR chunk swizzle

    u16x8 onesu;
#pragma unroll
    for (int j = 0; j < 8; ++j) onesu[j] = 0x3F80;   // bf16 1.0
    const bf16x8 ones = __builtin_bit_cast(bf16x8, onesu);

    for (int sidx = 0; sidx < 2; ++sidx) {
        const int qt = sidx ? (15 - pair) : pair;
        const int q0 = qt * 128;

        bf16x8 qf[2];
#pragma unroll
        for (int kk = 0; kk < 2; ++kk)
            qf[kk] = *(const bf16x8*)(Q + (rowbase + q0 + w * 16 + mm) * D_DIM
                                        + coff + kk * 32 + quad * 8);
        f32x4 o[4], lacc;
        lacc = (f32x4){0.f, 0.f, 0.f, 0.f};
#pragma unroll
        for (int hf = 0; hf < 4; ++hf) o[hf] = (f32x4){0.f, 0.f, 0.f, 0.f};

        const int nkt = 2 * qt + 2;
        const int qr = q0 + w * 16 + mm;          // this lane's q-row
        const int qrmax = q0 + w * 16 + 15;       // wave's max q-row
        const int m = w * 16 + mm;                // sP row

        // prologue: stage tile 0 into buf 0
        gload16(K  + (rowbase + sc_) * D_DIM + coff + sgk * 8, (void*)&sK[0][t * 8]);
        gload16(Vh + (size_t)sc_ * S_LEN + sgk * 8,            (void*)&sVT[0][t * 8]);

        for (int kt = 0; kt < nkt; ++kt) {
            const int buf = kt & 1;
            __syncthreads();   // buf's loads drained (issued a full phase ago)
            if (kt + 1 < nkt) {
                const int k1 = (kt + 1) * 64;
                gload16(K  + (rowbase + k1 + sc_) * D_DIM + coff + sgk * 8,
                        (void*)&sK[1 - buf][t * 8]);
                gload16(Vh + (size_t)sc_ * S_LEN + k1 + sgk * 8,
                        (void*)&sVT[1 - buf][t * 8]);
            }
            const int k0 = kt * 64;
            if (k0 > qrmax) continue;   // fully masked for this wave

            // S^T = K Q^T : A = K rows, B = Q rows
            f32x4 sacc[4];
#pragma unroll
            for (int kf = 0; kf < 4; ++kf) sacc[kf] = (f32x4){0.f, 0.f, 0.f, 0.f};
#pragma unroll
            for (int kk = 0; kk < 2; ++kk) {
                bf16x8 ak[4];
#pragma unroll
                for (int kf = 0; kf < 4; ++kf) {
                    int key = kf * 16 + mm;
                    int slot = (kk * 4 + quad) ^ (key & 7);
                    ak[kf] = *(const bf16x8*)&sK[buf][key * 64 + slot * 8];
                }
#pragma unroll
                for (int kf = 0; kf < 4; ++kf)
                    sacc[kf] = __builtin_amdgcn_mfma_f32_16x16x32_bf16(ak[kf], qf[kk], sacc[kf], 0, 0, 0);
            }

            // p = exp2(s), causal mask -> 0, pack to wave-private sP rows
            const bool needmask = (k0 + 63) > (q0 + w * 16);
#pragma unroll
            for (int kf = 0; kf < 4; ++kf) {
                float p[4];
#pragma unroll
                for (int r = 0; r < 4; ++r) {
                    p[r] = __builtin_amdgcn_exp2f(sacc[kf][r]);
                    if (needmask && (k0 + kf * 16 + quad * 4 + r) > qr) p[r] = 0.f;
                }
                unsigned lo = pack2(p[0], p[1]), hi = pack2(p[2], p[3]);
                int slot = (kf * 2 + (quad >> 1)) ^ (m & 7);
                *(unsigned long long*)&sP[m * 64 + slot * 8 + (quad & 1) * 4] =
                    ((unsigned long long)hi << 32) | lo;
            }

            // O += P V ; l += P * ones
#pragma unroll
            for (int kk = 0; kk < 2; ++kk) {
                bf16x8 pf, vf[4];
                {
                    int slot = (kk * 4 + quad) ^ (m & 7);
                    pf = *(const bf16x8*)&sP[m * 64 + slot * 8];
                }
#pragma unroll
                for (int hf = 0; hf < 4; ++hf) {
                    int hd = hf * 16 + mm;
                    int slot = (kk * 4 + quad) ^ (hd & 7);
                    vf[hf] = *(const bf16x8*)&sVT[buf][hd * 64 + slot * 8];
                }
                lacc = __builtin_amdgcn_mfma_f32_16x16x32_bf16(pf, ones, lacc, 0, 0, 0);
#pragma unroll
                for (int hf = 0; hf < 4; ++hf)
                    o[hf] = __builtin_amdgcn_mfma_f32_16x16x32_bf16(pf, vf[hf], o[hf], 0, 0, 0);
            }
        }
        __syncthreads();   // all compute done before next strip's prologue restages buf0

        // normalize (l already in C-layout) and store ctx
#pragma unroll
        for (int r = 0; r < 4; ++r) {
            float inv = 1.f / lacc[r];
            int row = q0 + w * 16 + quad * 4 + r;
#pragma unroll
            for (int hf = 0; hf < 4; ++hf)
                ctx[(rowbase + row) * D_DIM + coff + hf * 16 + mm] = f2bf(o[hf][r] * inv);
        }
    }
}

extern "C" void kernel_launch(void* const* d_in, const int* in_sizes, int n_in,
                              void* d_out, int out_size, void* d_ws, size_t ws_size,
                              hipStream_t stream)
{
    const float* x  = (const float*)d_in[0];
    const float* wq = (const float*)d_in[1];
    const float* wk = (const float*)d_in[2];
    const float* wv = (const float*)d_in[3];
    const float* wo = (const float*)d_in[4];

    const size_t XE = (size_t)M_ROWS * D_DIM;   // 8M elems
    const size_t WE = (size_t)D_DIM * D_DIM;    // 1M elems
    unsigned short* ws  = (unsigned short*)d_ws;
    unsigned short* xbf = ws;
    unsigned short* wt0 = xbf + XE;
    unsigned short* wt1 = wt0 + WE;
    unsigned short* wt2 = wt1 + WE;
    unsigned short* wt3 = wt2 + WE;
    unsigned short* qb  = wt3 + WE;
    unsigned short* kb  = qb + XE;
    unsigned short* vt  = kb + XE;      // V stored transposed per head
    unsigned short* cb  = vt + XE;      // ~80 MB total

    prep_k<<<dim3(4096 + 1024), 256, 0, stream>>>(x, wq, wk, wv, wo,
                                                  xbf, wt0, wt1, wt2, wt3);

    gemmqkv_k<<<dim3(512), 512, 0, stream>>>(xbf, wt0, qb, kb, vt);

    attn_k<<<dim3(8, BATCH * NH), 512, 0, stream>>>(qb, kb, vt, cb);

    gemmo_k<<<dim3(256), 512, 0, stream>>>(cb, wt3, (float*)d_out);
}

// Round 4
// 244.034 us; speedup vs baseline: 1.0798x; 1.0337x over previous
//
#include <hip/hip_runtime.h>

#define S_LEN 2048
#define D_DIM 1024
#define NH    16
#define HD    64
#define BATCH 4
#define M_ROWS 8192

typedef __attribute__((ext_vector_type(8))) short bf16x8;   // 8 bf16 = 4 VGPR
typedef __attribute__((ext_vector_type(4))) float f32x4;
typedef __attribute__((ext_vector_type(8))) unsigned short u16x8;

__device__ __forceinline__ unsigned short f2bf(float f) {
    unsigned u = __builtin_bit_cast(unsigned, f);
    u = (u + 0x7fffu + ((u >> 16) & 1u)) >> 16;   // RNE
    return (unsigned short)u;
}
// round-half-up pack of two f32 -> packed bf16x2 (bias cancels: l from same P)
__device__ __forceinline__ unsigned pack2(float a, float b) {
    unsigned ua = __builtin_bit_cast(unsigned, a);
    unsigned ub = __builtin_bit_cast(unsigned, b);
    return ((ua + 0x8000u) >> 16) | ((ub + 0x8000u) & 0xffff0000u);
}

__device__ __forceinline__ void gload16(const void* g, void* l) {
    __builtin_amdgcn_global_load_lds((const __attribute__((address_space(1))) unsigned*)g,
                                     (__attribute__((address_space(3))) unsigned*)l,
                                     16, 0, 0);
}

template<int N> __device__ __forceinline__ void vmwait() {
    if constexpr (N == 0)      asm volatile("s_waitcnt vmcnt(0)" ::: "memory");
    else if constexpr (N == 3) asm volatile("s_waitcnt vmcnt(3)" ::: "memory");
    else if constexpr (N == 5) asm volatile("s_waitcnt vmcnt(5)" ::: "memory");
}

// ---------------------------------------------------------------------------
// Merged prep: blocks [0,4096) cast x fp32->bf16; blocks [4096,5120) build
// W^T bf16 (wq pre-scaled by 0.125*log2(e)). One launch instead of two.
// ---------------------------------------------------------------------------
__global__ __launch_bounds__(256) void prep_k(const float* __restrict__ x,
                                              const float* __restrict__ w0, const float* __restrict__ w1,
                                              const float* __restrict__ w2, const float* __restrict__ w3,
                                              unsigned short* __restrict__ xbf,
                                              unsigned short* __restrict__ o0, unsigned short* __restrict__ o1,
                                              unsigned short* __restrict__ o2, unsigned short* __restrict__ o3) {
    __shared__ float sT[64][65];
    const int t = threadIdx.x;
    if (blockIdx.x < 4096) {
        size_t i = (size_t)blockIdx.x * 256 + t;
        const float4* xf = (const float4*)x;
        float4 a = xf[2 * i], b = xf[2 * i + 1];
        u16x8 v;
        v[0] = f2bf(a.x); v[1] = f2bf(a.y); v[2] = f2bf(a.z); v[3] = f2bf(a.w);
        v[4] = f2bf(b.x); v[5] = f2bf(b.y); v[6] = f2bf(b.z); v[7] = f2bf(b.w);
        *(u16x8*)(xbf + i * 8) = v;
        return;
    }
    const int wb = blockIdx.x - 4096;          // 0..1023
    const int z = wb >> 8;                     // weight index
    const float* w; unsigned short* o;
    switch (z) {
        case 0: w = w0; o = o0; break;
        case 1: w = w1; o = o1; break;
        case 2: w = w2; o = o2; break;
        default: w = w3; o = o3; break;
    }
    const float sc = (z == 0) ? 0.18033688011112042f : 1.0f;
    const int n0 = (wb & 15) * 64, k0 = ((wb >> 4) & 15) * 64;
    const int r = t >> 4, cq = t & 15;
#pragma unroll
    for (int it = 0; it < 4; ++it) {
        int k = r + it * 16;
        float4 v = *(const float4*)&w[(size_t)(k0 + k) * D_DIM + n0 + cq * 4];
        sT[k][cq * 4 + 0] = v.x; sT[k][cq * 4 + 1] = v.y;
        sT[k][cq * 4 + 2] = v.z; sT[k][cq * 4 + 3] = v.w;
    }
    __syncthreads();
    const int n = t >> 2, ch = t & 3;
    union { unsigned short s[8]; uint4 v; } p0, p1;
#pragma unroll
    for (int j = 0; j < 8; ++j) p0.s[j] = f2bf(sT[ch * 16 + j][n] * sc);
#pragma unroll
    for (int j = 0; j < 8; ++j) p1.s[j] = f2bf(sT[ch * 16 + 8 + j][n] * sc);
    *(uint4*)&o[(size_t)(n0 + n) * D_DIM + k0 + ch * 16]     = p0.v;
    *(uint4*)&o[(size_t)(n0 + n) * D_DIM + k0 + ch * 16 + 8] = p1.v;
}

// ---------------------------------------------------------------------------
// Fine-phase GEMM core. Tile = (MFRAG*32) x (NFRAG*64), BK=32. 8 waves as
// 2M x 4N: per-wave output = MFRAG*16 rows x NFRAG*16 cols, acc[MFRAG][NFRAG].
// Tile cadence analysis (R2/R3): per-tile time ~2900cy regardless of barrier
// count -> maximize FLOP/tile (BM*BN/(BM+BN)) and use the m201 fine-phase
// rhythm. Each K-32 tile = MFRAG/2 phases: {2 af ds_read (+NFRAG bv in p0) |
// 1-2 gloads for tile T+2 | barrier | lgkmcnt(0) | setprio(1) 2*NFRAG MFMA
// setprio(0) | [vmcnt(NGLD) counted, last phase] | barrier}. 3-slot LDS ring,
// 1 full tile always in flight across barriers (T4); drains only at T=30.
// XOR chunk swizzle both sides (write pre-swizzles global src; read
// xs = quad ^ ((mm>>1)&3)) -> measured 0 bank conflicts (R2/R3).
// ---------------------------------------------------------------------------
template<int MFRAG, int NFRAG, int AGLD, int BGLD>
__device__ __forceinline__ void gemm_core(const unsigned short* __restrict__ A,
                                          const unsigned short* __restrict__ Bt,
                                          unsigned short* __restrict__ sA,
                                          unsigned short* __restrict__ sB,
                                          int m0, int n0, int t,
                                          f32x4 (&acc)[MFRAG][NFRAG])
{
    constexpr int NGLD  = AGLD + BGLD;
    constexpr int ASLOT = AGLD * 4096;     // elems per ring slot
    constexpr int BSLOT = BGLD * 4096;
    constexpr int NPH   = MFRAG / 2;       // phases per K-32 tile

    const int lane = t & 63, wid = t >> 6;
    const int mm = lane & 15, quad = lane >> 4;
    const int wm = wid >> 2, wn = wid & 3;

    // staging: thread t covers (row t>>2 [+i*128], chunk t&3) per pass;
    // pre-swizzled global chunk g = j ^ ((row>>1)&3)  (involution; row+128
    // preserves (row>>1)&3)
    const int sr = t >> 2;
    const int sg = (t & 3) ^ ((sr >> 1) & 3);
    const unsigned short* asrc = A  + (size_t)(m0 + sr) * D_DIM + sg * 8;
    const unsigned short* bsrc = Bt + (size_t)(n0 + sr) * D_DIM + sg * 8;
    unsigned short* dA = sA + t * 8;
    unsigned short* dB = sB + t * 8;

    // read-side geometry (all frag row offsets are multiples of 16 so the
    // row-XOR folds to the per-thread constant ((mm>>1)&3))
    const int al = wm * (MFRAG * 16) + mm;
    const int bl = wn * (NFRAG * 16) + mm;
    const int xs = quad ^ ((mm >> 1) & 3);

    // prologue: tiles 0,1 into slots 0,1; confirm tile 0, keep tile 1 in flight
#pragma unroll
    for (int pt = 0; pt < 2; ++pt) {
        const int ko = pt * 32;
#pragma unroll
        for (int i = 0; i < AGLD; ++i)
            gload16(asrc + (size_t)i * 128 * D_DIM + ko, dA + pt * ASLOT + i * 4096);
#pragma unroll
        for (int i = 0; i < BGLD; ++i)
            gload16(bsrc + (size_t)i * 128 * D_DIM + ko, dB + pt * BSLOT + i * 4096);
    }
    vmwait<NGLD>();
    __builtin_amdgcn_s_barrier();

    int sRead = 0, sWrite = 2;
    for (int T = 0; T < 32; ++T) {
        const int soA = sRead * ASLOT, soB = sRead * BSLOT;
        const int woA = sWrite * ASLOT, woB = sWrite * BSLOT;
        const int ko = (T + 2) * 32;
        const bool st = (T <= 29);

        bf16x8 bv[NFRAG];
#pragma unroll
        for (int p = 0; p < NPH; ++p) {
            if (p == 0) {
#pragma unroll
                for (int nf = 0; nf < NFRAG; ++nf)
                    bv[nf] = *(const bf16x8*)&sB[soB + (bl + nf * 16) * 32 + xs * 8];
            }
            bf16x8 af0 = *(const bf16x8*)&sA[soA + (al + (2 * p) * 16) * 32 + xs * 8];
            bf16x8 af1 = *(const bf16x8*)&sA[soA + (al + (2 * p + 1) * 16) * 32 + xs * 8];

            if (st) {
                if (p == 0) {
#pragma unroll
                    for (int i = 0; i < AGLD; ++i)
                        gload16(asrc + (size_t)i * 128 * D_DIM + ko, dA + woA + i * 4096);
                } else {
#pragma unroll
                    for (int i = 0; i < BGLD; ++i)
                        if ((i % (NPH - 1)) == p - 1)
                            gload16(bsrc + (size_t)i * 128 * D_DIM + ko, dB + woB + i * 4096);
                }
            }

            __builtin_amdgcn_s_barrier();
            asm volatile("s_waitcnt lgkmcnt(0)" ::: "memory");
            __builtin_amdgcn_s_setprio(1);
#pragma unroll
            for (int nf = 0; nf < NFRAG; ++nf) {
                acc[2 * p][nf]     = __builtin_amdgcn_mfma_f32_16x16x32_bf16(af0, bv[nf], acc[2 * p][nf], 0, 0, 0);
                acc[2 * p + 1][nf] = __builtin_amdgcn_mfma_f32_16x16x32_bf16(af1, bv[nf], acc[2 * p + 1][nf], 0, 0, 0);
            }
            __builtin_amdgcn_s_setprio(0);
            if (p == NPH - 1) {
                if (T <= 29)      vmwait<NGLD>();   // tile T+1 confirmed, T+2 in flight
                else if (T == 30) vmwait<0>();      // drain: tile 31 confirmed
            }
            __builtin_amdgcn_s_barrier();
        }

        sRead  = (sRead  == 2) ? 0 : sRead + 1;
        sWrite = (sWrite == 2) ? 0 : sWrite + 1;
    }
}

// ---------------------------------------------------------------------------
// Fused QKV GEMM: BM=256, BN=384 -> grid 32m x 8n = 256 blocks = 1.0 exact
// round, 153.6 FLOP/staged-byte (max over feasible shapes). 12.6 MFLOP per
// tile-step amortizes the ~2900cy fixed cadence. B^T = [Wq^T|Wk^T|Wv^T]
// contiguous; epilogue routes per 16-wide fragment. LDS 120KB (3-slot ring).
// XCD chunking: 4 m-tiles x all n per XCD -> A panel 2MB L2-resident.
// ---------------------------------------------------------------------------
__global__ __launch_bounds__(512, 2) void gemmqkv_k(const unsigned short* __restrict__ A,
                                                    const unsigned short* __restrict__ Bt,
                                                    unsigned short* __restrict__ qb,
                                                    unsigned short* __restrict__ kb,
                                                    unsigned short* __restrict__ vt)
{
    __shared__ unsigned short sA[3 * 2 * 4096];    // 48KB
    __shared__ unsigned short sB[3 * 3 * 4096];    // 72KB
    const int t = threadIdx.x;
    const int bid = blockIdx.x;                    // 256 = 8 XCD * 32
    const int wg = (bid & 7) * 32 + (bid >> 3);
    const int mt = wg >> 3, nt = wg & 7;
    const int m0 = mt * 256, n0 = nt * 384;

    f32x4 acc[8][6];
#pragma unroll
    for (int i = 0; i < 8; ++i)
#pragma unroll
        for (int j = 0; j < 6; ++j) acc[i][j] = (f32x4){0.f, 0.f, 0.f, 0.f};

    gemm_core<8, 6, 2, 3>(A, Bt, sA, sB, m0, n0, t, acc);

    const int lane = t & 63, wid = t >> 6;
    const int mm = lane & 15, quad = lane >> 4;
    const int wm = wid >> 2, wn = wid & 3;

#pragma unroll
    for (int nf = 0; nf < 6; ++nf) {
        const int c0 = n0 + wn * 96 + nf * 16;     // 16-aligned -> widx uniform
        const int widx = c0 >> 10, nl0 = c0 & 1023;
        if (widx == 2) {
            // V: write transposed per head (16-wide frag never crosses a head)
            const int h = nl0 >> 6, hd = (nl0 & 63) + mm;
#pragma unroll
            for (int mf = 0; mf < 8; ++mf) {
                int rglob = m0 + wm * 128 + mf * 16 + quad * 4;
                int bb = rglob >> 11, ss = rglob & (S_LEN - 1);
                union { unsigned short s[4]; unsigned long long ll; } pk;
#pragma unroll
                for (int r = 0; r < 4; ++r) pk.s[r] = f2bf(acc[mf][nf][r]);
                *(unsigned long long*)&vt[((size_t)(bb * NH + h) * HD + hd) * S_LEN + ss] = pk.ll;
            }
        } else {
            unsigned short* outp = widx ? kb : qb;
#pragma unroll
            for (int mf = 0; mf < 8; ++mf)
#pragma unroll
                for (int r = 0; r < 4; ++r)
                    outp[(size_t)(m0 + wm * 128 + mf * 16 + quad * 4 + r) * D_DIM +
                         nl0 + mm] = f2bf(acc[mf][nf][r]);
        }
    }
}

// ---------------------------------------------------------------------------
// Output GEMM: out_fp32 = ctx_bf16 * WoT^T. BM=128, BN=256 -> 64m x 4n =
// 256 blocks = 1.0 exact round. Same fine-phase core (2 phases x 8 MFMA).
// XCD chunking 8m x 4n: A 2MB + B 2MB both L2-resident per XCD.
// ---------------------------------------------------------------------------
__global__ __launch_bounds__(512, 2) void gemmo_k(const unsigned short* __restrict__ A,
                                                  const unsigned short* __restrict__ Bt,
                                                  float* __restrict__ C)
{
    __shared__ unsigned short sA[3 * 4096];        // 24KB
    __shared__ unsigned short sB[3 * 2 * 4096];    // 48KB
    const int t = threadIdx.x;
    const int bid = blockIdx.x;                    // 256 = 8 XCD * 32
    const int wg = (bid & 7) * 32 + (bid >> 3);
    const int mt = wg >> 2, nt = wg & 3;
    const int m0 = mt * 128, n0 = nt * 256;

    f32x4 acc[4][4];
#pragma unroll
    for (int i = 0; i < 4; ++i)
#pragma unroll
        for (int j = 0; j < 4; ++j) acc[i][j] = (f32x4){0.f, 0.f, 0.f, 0.f};

    gemm_core<4, 4, 1, 2>(A, Bt, sA, sB, m0, n0, t, acc);

    const int lane = t & 63, wid = t >> 6;
    const int mm = lane & 15, quad = lane >> 4;
    const int wm = wid >> 2, wn = wid & 3;

#pragma unroll
    for (int mf = 0; mf < 4; ++mf)
#pragma unroll
        for (int nf = 0; nf < 4; ++nf)
#pragma unroll
            for (int r = 0; r < 4; ++r)
                C[(size_t)(m0 + wm * 64 + mf * 16 + quad * 4 + r) * D_DIM +
                  n0 + wn * 64 + nf * 16 + mm] = acc[mf][nf][r];
}

// ---------------------------------------------------------------------------
// Fused causal flash attention (verified config: 74.5 us).
// 512 threads (8 waves), 16 q-rows/wave, block covers strips {qt, 15-qt}
// (uniform 34 k-tiles of 64 keys). K/V^T double-buffered, prefetch issued
// right after the per-tile barrier (long compute phase hides the drain).
// l computed via MFMA against all-ones B; sP rows are wave-private.
// ---------------------------------------------------------------------------
__global__ __launch_bounds__(512, 4) void attn_k(const unsigned short* __restrict__ Q,
                                                 const unsigned short* __restrict__ K,
                                                 const unsigned short* __restrict__ Vt,
                                                 unsigned short* __restrict__ ctx)
{
    __shared__ unsigned short sK [2][64 * 64];   // [buf][key][hd]   2x8KB
    __shared__ unsigned short sVT[2][64 * 64];   // [buf][hd][key]   2x8KB
    __shared__ unsigned short sP [128 * 64];     // [qrow][key]      16KB
    const int t = threadIdx.x;
    const int lane = t & 63, w = t >> 6;          // w = 0..7
    const int mm = lane & 15, quad = lane >> 4;
    const int pair = blockIdx.x, bh = blockIdx.y;
    const int b = bh >> 4, hh = bh & 15;
    const size_t rowbase = (size_t)b * S_LEN;
    const int coff = hh * HD;
    const unsigned short* Vh = Vt + (size_t)bh * HD * S_LEN;

    // staging geometry: 512 lanes cover one 64x128B tile per buffer
    const int sc_ = t >> 3, sj = t & 7;
    const int sgk = sj ^ (sc_ & 7);               // XOR chunk swizzle

    u16x8 onesu;
#pragma unroll
    for (int j = 0; j < 8; ++j) onesu[j] = 0x3F80;   // bf16 1.0
    const bf16x8 ones = __builtin_bit_cast(bf16x8, onesu);

    for (int sidx = 0; sidx < 2; ++sidx) {
        const int qt = sidx ? (15 - pair) : pair;
        const int q0 = qt * 128;

        bf16x8 qf[2];
#pragma unroll
        for (int kk = 0; kk < 2; ++kk)
            qf[kk] = *(const bf16x8*)(Q + (rowbase + q0 + w * 16 + mm) * D_DIM
                                        + coff + kk * 32 + quad * 8);
        f32x4 o[4], lacc;
        lacc = (f32x4){0.f, 0.f, 0.f, 0.f};
#pragma unroll
        for (int hf = 0; hf < 4; ++hf) o[hf] = (f32x4){0.f, 0.f, 0.f, 0.f};

        const int nkt = 2 * qt + 2;
        const int qr = q0 + w * 16 + mm;          // this lane's q-row
        const int qrmax = q0 + w * 16 + 15;       // wave's max q-row
        const int m = w * 16 + mm;                // sP row

        // prologue: stage tile 0 into buf 0
        gload16(K  + (rowbase + sc_) * D_DIM + coff + sgk * 8, (void*)&sK[0][t * 8]);
        gload16(Vh + (size_t)sc_ * S_LEN + sgk * 8,            (void*)&sVT[0][t * 8]);

        for (int kt = 0; kt < nkt; ++kt) {
            const int buf = kt & 1;
            __syncthreads();   // buf's loads drained (issued a full phase ago)
            if (kt + 1 < nkt) {
                const int k1 = (kt + 1) * 64;
                gload16(K  + (rowbase + k1 + sc_) * D_DIM + coff + sgk * 8,
                        (void*)&sK[1 - buf][t * 8]);
                gload16(Vh + (size_t)sc_ * S_LEN + k1 + sgk * 8,
                        (void*)&sVT[1 - buf][t * 8]);
            }
            const int k0 = kt * 64;
            if (k0 > qrmax) continue;   // fully masked for this wave

            // S^T = K Q^T : A = K rows, B = Q rows
            f32x4 sacc[4];
#pragma unroll
            for (int kf = 0; kf < 4; ++kf) sacc[kf] = (f32x4){0.f, 0.f, 0.f, 0.f};
#pragma unroll
            for (int kk = 0; kk < 2; ++kk) {
                bf16x8 ak[4];
#pragma unroll
                for (int kf = 0; kf < 4; ++kf) {
                    int key = kf * 16 + mm;
                    int slot = (kk * 4 + quad) ^ (key & 7);
                    ak[kf] = *(const bf16x8*)&sK[buf][key * 64 + slot * 8];
                }
#pragma unroll
                for (int kf = 0; kf < 4; ++kf)
                    sacc[kf] = __builtin_amdgcn_mfma_f32_16x16x32_bf16(ak[kf], qf[kk], sacc[kf], 0, 0, 0);
            }

            // p = exp2(s), causal mask -> 0, pack to wave-private sP rows
            const bool needmask = (k0 + 63) > (q0 + w * 16);
#pragma unroll
            for (int kf = 0; kf < 4; ++kf) {
                float p[4];
#pragma unroll
                for (int r = 0; r < 4; ++r) {
                    p[r] = __builtin_amdgcn_exp2f(sacc[kf][r]);
                    if (needmask && (k0 + kf * 16 + quad * 4 + r) > qr) p[r] = 0.f;
                }
                unsigned lo = pack2(p[0], p[1]), hi = pack2(p[2], p[3]);
                int slot = (kf * 2 + (quad >> 1)) ^ (m & 7);
                *(unsigned long long*)&sP[m * 64 + slot * 8 + (quad & 1) * 4] =
                    ((unsigned long long)hi << 32) | lo;
            }

            // O += P V ; l += P * ones
#pragma unroll
            for (int kk = 0; kk < 2; ++kk) {
                bf16x8 pf, vf[4];
                {
                    int slot = (kk * 4 + quad) ^ (m & 7);
                    pf = *(const bf16x8*)&sP[m * 64 + slot * 8];
                }
#pragma unroll
                for (int hf = 0; hf < 4; ++hf) {
                    int hd = hf * 16 + mm;
                    int slot = (kk * 4 + quad) ^ (hd & 7);
                    vf[hf] = *(const bf16x8*)&sVT[buf][hd * 64 + slot * 8];
                }
                lacc = __builtin_amdgcn_mfma_f32_16x16x32_bf16(pf, ones, lacc, 0, 0, 0);
#pragma unroll
                for (int hf = 0; hf < 4; ++hf)
                    o[hf] = __builtin_amdgcn_mfma_f32_16x16x32_bf16(pf, vf[hf], o[hf], 0, 0, 0);
            }
        }
        __syncthreads();   // all compute done before next strip's prologue restages buf0

        // normalize (l already in C-layout) and store ctx
#pragma unroll
        for (int r = 0; r < 4; ++r) {
            float inv = 1.f / lacc[r];
            int row = q0 + w * 16 + quad * 4 + r;
#pragma unroll
            for (int hf = 0; hf < 4; ++hf)
                ctx[(rowbase + row) * D_DIM + coff + hf * 16 + mm] = f2bf(o[hf][r] * inv);
        }
    }
}

extern "C" void kernel_launch(void* const* d_in, const int* in_sizes, int n_in,
                              void* d_out, int out_size, void* d_ws, size_t ws_size,
                              hipStream_t stream)
{
    const float* x  = (const float*)d_in[0];
    const float* wq = (const float*)d_in[1];
    const float* wk = (const float*)d_in[2];
    const float* wv = (const float*)d_in[3];
    const float* wo = (const float*)d_in[4];

    const size_t XE = (size_t)M_ROWS * D_DIM;   // 8M elems
    const size_t WE = (size_t)D_DIM * D_DIM;    // 1M elems
    unsigned short* ws  = (unsigned short*)d_ws;
    unsigned short* xbf = ws;
    unsigned short* wt0 = xbf + XE;
    unsigned short* wt1 = wt0 + WE;
    unsigned short* wt2 = wt1 + WE;
    unsigned short* wt3 = wt2 + WE;
    unsigned short* qb  = wt3 + WE;
    unsigned short* kb  = qb + XE;
    unsigned short* vt  = kb + XE;      // V stored transposed per head
    unsigned short* cb  = vt + XE;      // ~80 MB total

    prep_k<<<dim3(4096 + 1024), 256, 0, stream>>>(x, wq, wk, wv, wo,
                                                  xbf, wt0, wt1, wt2, wt3);

    gemmqkv_k<<<dim3(256), 512, 0, stream>>>(xbf, wt0, qb, kb, vt);

    attn_k<<<dim3(8, BATCH * NH), 512, 0, stream>>>(qb, kb, vt, cb);

    gemmo_k<<<dim3(256), 512, 0, stream>>>(cb, wt3, (float*)d_out);
}

// Round 5
// 239.865 us; speedup vs baseline: 1.0986x; 1.0174x over previous
//
#include <hip/hip_runtime.h>

#define S_LEN 2048
#define D_DIM 1024
#define NH    16
#define HD    64
#define BATCH 4
#define M_ROWS 8192

typedef __attribute__((ext_vector_type(8))) short bf16x8;   // 8 bf16 = 4 VGPR
typedef __attribute__((ext_vector_type(4))) float f32x4;
typedef __attribute__((ext_vector_type(8))) unsigned short u16x8;

__device__ __forceinline__ unsigned short f2bf(float f) {
    unsigned u = __builtin_bit_cast(unsigned, f);
    u = (u + 0x7fffu + ((u >> 16) & 1u)) >> 16;   // RNE
    return (unsigned short)u;
}
// round-half-up pack of two f32 -> packed bf16x2 (bias cancels: l from same P)
__device__ __forceinline__ unsigned pack2(float a, float b) {
    unsigned ua = __builtin_bit_cast(unsigned, a);
    unsigned ub = __builtin_bit_cast(unsigned, b);
    return ((ua + 0x8000u) >> 16) | ((ub + 0x8000u) & 0xffff0000u);
}

__device__ __forceinline__ void gload16(const void* g, void* l) {
    __builtin_amdgcn_global_load_lds((const __attribute__((address_space(1))) unsigned*)g,
                                     (__attribute__((address_space(3))) unsigned*)l,
                                     16, 0, 0);
}

template<int N> __device__ __forceinline__ void vmwait() {
    if constexpr (N == 0)      asm volatile("s_waitcnt vmcnt(0)" ::: "memory");
    else if constexpr (N == 3) asm volatile("s_waitcnt vmcnt(3)" ::: "memory");
    else if constexpr (N == 5) asm volatile("s_waitcnt vmcnt(5)" ::: "memory");
}

// ---------------------------------------------------------------------------
// Merged prep: blocks [0,4096) cast x fp32->bf16; blocks [4096,5120) build
// W^T bf16 (wq pre-scaled by 0.125*log2(e)). One launch instead of two.
// ---------------------------------------------------------------------------
__global__ __launch_bounds__(256) void prep_k(const float* __restrict__ x,
                                              const float* __restrict__ w0, const float* __restrict__ w1,
                                              const float* __restrict__ w2, const float* __restrict__ w3,
                                              unsigned short* __restrict__ xbf,
                                              unsigned short* __restrict__ o0, unsigned short* __restrict__ o1,
                                              unsigned short* __restrict__ o2, unsigned short* __restrict__ o3) {
    __shared__ float sT[64][65];
    const int t = threadIdx.x;
    if (blockIdx.x < 4096) {
        size_t i = (size_t)blockIdx.x * 256 + t;
        const float4* xf = (const float4*)x;
        float4 a = xf[2 * i], b = xf[2 * i + 1];
        u16x8 v;
        v[0] = f2bf(a.x); v[1] = f2bf(a.y); v[2] = f2bf(a.z); v[3] = f2bf(a.w);
        v[4] = f2bf(b.x); v[5] = f2bf(b.y); v[6] = f2bf(b.z); v[7] = f2bf(b.w);
        *(u16x8*)(xbf + i * 8) = v;
        return;
    }
    const int wb = blockIdx.x - 4096;          // 0..1023
    const int z = wb >> 8;                     // weight index
    const float* w; unsigned short* o;
    switch (z) {
        case 0: w = w0; o = o0; break;
        case 1: w = w1; o = o1; break;
        case 2: w = w2; o = o2; break;
        default: w = w3; o = o3; break;
    }
    const float sc = (z == 0) ? 0.18033688011112042f : 1.0f;
    const int n0 = (wb & 15) * 64, k0 = ((wb >> 4) & 15) * 64;
    const int r = t >> 4, cq = t & 15;
#pragma unroll
    for (int it = 0; it < 4; ++it) {
        int k = r + it * 16;
        float4 v = *(const float4*)&w[(size_t)(k0 + k) * D_DIM + n0 + cq * 4];
        sT[k][cq * 4 + 0] = v.x; sT[k][cq * 4 + 1] = v.y;
        sT[k][cq * 4 + 2] = v.z; sT[k][cq * 4 + 3] = v.w;
    }
    __syncthreads();
    const int n = t >> 2, ch = t & 3;
    union { unsigned short s[8]; uint4 v; } p0, p1;
#pragma unroll
    for (int j = 0; j < 8; ++j) p0.s[j] = f2bf(sT[ch * 16 + j][n] * sc);
#pragma unroll
    for (int j = 0; j < 8; ++j) p1.s[j] = f2bf(sT[ch * 16 + 8 + j][n] * sc);
    *(uint4*)&o[(size_t)(n0 + n) * D_DIM + k0 + ch * 16]     = p0.v;
    *(uint4*)&o[(size_t)(n0 + n) * D_DIM + k0 + ch * 16 + 8] = p1.v;
}

// ---------------------------------------------------------------------------
// Fine-phase GEMM core. Tile = (MFRAG*32) x (NFRAG*64), BK=32. 8 waves as
// 2M x 4N: per-wave output = MFRAG*16 rows x NFRAG*16 cols, acc[MFRAG][NFRAG].
// Tile cadence analysis (R2/R3): per-tile time ~2900cy regardless of barrier
// count -> maximize FLOP/tile (BM*BN/(BM+BN)) and use the m201 fine-phase
// rhythm. 3-slot LDS ring, 1 full tile always in flight across barriers (T4).
// XOR chunk swizzle both sides -> measured 0 bank conflicts (R2/R3).
// ---------------------------------------------------------------------------
template<int MFRAG, int NFRAG, int AGLD, int BGLD>
__device__ __forceinline__ void gemm_core(const unsigned short* __restrict__ A,
                                          const unsigned short* __restrict__ Bt,
                                          unsigned short* __restrict__ sA,
                                          unsigned short* __restrict__ sB,
                                          int m0, int n0, int t,
                                          f32x4 (&acc)[MFRAG][NFRAG])
{
    constexpr int NGLD  = AGLD + BGLD;
    constexpr int ASLOT = AGLD * 4096;     // elems per ring slot
    constexpr int BSLOT = BGLD * 4096;
    constexpr int NPH   = MFRAG / 2;       // phases per K-32 tile

    const int lane = t & 63, wid = t >> 6;
    const int mm = lane & 15, quad = lane >> 4;
    const int wm = wid >> 2, wn = wid & 3;

    // staging: thread t covers (row t>>2 [+i*128], chunk t&3) per pass;
    // pre-swizzled global chunk g = j ^ ((row>>1)&3)  (involution; row+128
    // preserves (row>>1)&3)
    const int sr = t >> 2;
    const int sg = (t & 3) ^ ((sr >> 1) & 3);
    const unsigned short* asrc = A  + (size_t)(m0 + sr) * D_DIM + sg * 8;
    const unsigned short* bsrc = Bt + (size_t)(n0 + sr) * D_DIM + sg * 8;
    unsigned short* dA = sA + t * 8;
    unsigned short* dB = sB + t * 8;

    // read-side geometry (all frag row offsets are multiples of 16 so the
    // row-XOR folds to the per-thread constant ((mm>>1)&3))
    const int al = wm * (MFRAG * 16) + mm;
    const int bl = wn * (NFRAG * 16) + mm;
    const int xs = quad ^ ((mm >> 1) & 3);

    // prologue: tiles 0,1 into slots 0,1; confirm tile 0, keep tile 1 in flight
#pragma unroll
    for (int pt = 0; pt < 2; ++pt) {
        const int ko = pt * 32;
#pragma unroll
        for (int i = 0; i < AGLD; ++i)
            gload16(asrc + (size_t)i * 128 * D_DIM + ko, dA + pt * ASLOT + i * 4096);
#pragma unroll
        for (int i = 0; i < BGLD; ++i)
            gload16(bsrc + (size_t)i * 128 * D_DIM + ko, dB + pt * BSLOT + i * 4096);
    }
    vmwait<NGLD>();
    __builtin_amdgcn_s_barrier();

    int sRead = 0, sWrite = 2;
    for (int T = 0; T < 32; ++T) {
        const int soA = sRead * ASLOT, soB = sRead * BSLOT;
        const int woA = sWrite * ASLOT, woB = sWrite * BSLOT;
        const int ko = (T + 2) * 32;
        const bool st = (T <= 29);

        bf16x8 bv[NFRAG];
#pragma unroll
        for (int p = 0; p < NPH; ++p) {
            if (p == 0) {
#pragma unroll
                for (int nf = 0; nf < NFRAG; ++nf)
                    bv[nf] = *(const bf16x8*)&sB[soB + (bl + nf * 16) * 32 + xs * 8];
            }
            bf16x8 af0 = *(const bf16x8*)&sA[soA + (al + (2 * p) * 16) * 32 + xs * 8];
            bf16x8 af1 = *(const bf16x8*)&sA[soA + (al + (2 * p + 1) * 16) * 32 + xs * 8];

            if (st) {
                if (p == 0) {
#pragma unroll
                    for (int i = 0; i < AGLD; ++i)
                        gload16(asrc + (size_t)i * 128 * D_DIM + ko, dA + woA + i * 4096);
                } else {
#pragma unroll
                    for (int i = 0; i < BGLD; ++i)
                        if ((i % (NPH - 1)) == p - 1)
                            gload16(bsrc + (size_t)i * 128 * D_DIM + ko, dB + woB + i * 4096);
                }
            }

            __builtin_amdgcn_s_barrier();
            asm volatile("s_waitcnt lgkmcnt(0)" ::: "memory");
            __builtin_amdgcn_s_setprio(1);
#pragma unroll
            for (int nf = 0; nf < NFRAG; ++nf) {
                acc[2 * p][nf]     = __builtin_amdgcn_mfma_f32_16x16x32_bf16(af0, bv[nf], acc[2 * p][nf], 0, 0, 0);
                acc[2 * p + 1][nf] = __builtin_amdgcn_mfma_f32_16x16x32_bf16(af1, bv[nf], acc[2 * p + 1][nf], 0, 0, 0);
            }
            __builtin_amdgcn_s_setprio(0);
            if (p == NPH - 1) {
                if (T <= 29)      vmwait<NGLD>();   // tile T+1 confirmed, T+2 in flight
                else if (T == 30) vmwait<0>();      // drain: tile 31 confirmed
            }
            __builtin_amdgcn_s_barrier();
        }

        sRead  = (sRead  == 2) ? 0 : sRead + 1;
        sWrite = (sWrite == 2) ? 0 : sWrite + 1;
    }
}

// ---------------------------------------------------------------------------
// Fused QKV GEMM: BM=256, BN=384 -> grid 32m x 8n = 256 blocks = 1.0 exact
// round, 153.6 FLOP/staged-byte. B^T = [Wq^T|Wk^T|Wv^T] contiguous; epilogue
// routes per 16-wide fragment. LDS 120KB (3-slot ring). XCD chunking:
// 4 m-tiles x all n per XCD -> A panel 2MB L2-resident.
// ---------------------------------------------------------------------------
__global__ __launch_bounds__(512, 2) void gemmqkv_k(const unsigned short* __restrict__ A,
                                                    const unsigned short* __restrict__ Bt,
                                                    unsigned short* __restrict__ qb,
                                                    unsigned short* __restrict__ kb,
                                                    unsigned short* __restrict__ vt)
{
    __shared__ unsigned short sA[3 * 2 * 4096];    // 48KB
    __shared__ unsigned short sB[3 * 3 * 4096];    // 72KB
    const int t = threadIdx.x;
    const int bid = blockIdx.x;                    // 256 = 8 XCD * 32
    const int wg = (bid & 7) * 32 + (bid >> 3);
    const int mt = wg >> 3, nt = wg & 7;
    const int m0 = mt * 256, n0 = nt * 384;

    f32x4 acc[8][6];
#pragma unroll
    for (int i = 0; i < 8; ++i)
#pragma unroll
        for (int j = 0; j < 6; ++j) acc[i][j] = (f32x4){0.f, 0.f, 0.f, 0.f};

    gemm_core<8, 6, 2, 3>(A, Bt, sA, sB, m0, n0, t, acc);

    const int lane = t & 63, wid = t >> 6;
    const int mm = lane & 15, quad = lane >> 4;
    const int wm = wid >> 2, wn = wid & 3;

#pragma unroll
    for (int nf = 0; nf < 6; ++nf) {
        const int c0 = n0 + wn * 96 + nf * 16;     // 16-aligned -> widx uniform
        const int widx = c0 >> 10, nl0 = c0 & 1023;
        if (widx == 2) {
            // V: write transposed per head (16-wide frag never crosses a head)
            const int h = nl0 >> 6, hd = (nl0 & 63) + mm;
#pragma unroll
            for (int mf = 0; mf < 8; ++mf) {
                int rglob = m0 + wm * 128 + mf * 16 + quad * 4;
                int bb = rglob >> 11, ss = rglob & (S_LEN - 1);
                union { unsigned short s[4]; unsigned long long ll; } pk;
#pragma unroll
                for (int r = 0; r < 4; ++r) pk.s[r] = f2bf(acc[mf][nf][r]);
                *(unsigned long long*)&vt[((size_t)(bb * NH + h) * HD + hd) * S_LEN + ss] = pk.ll;
            }
        } else {
            unsigned short* outp = widx ? kb : qb;
#pragma unroll
            for (int mf = 0; mf < 8; ++mf)
#pragma unroll
                for (int r = 0; r < 4; ++r)
                    outp[(size_t)(m0 + wm * 128 + mf * 16 + quad * 4 + r) * D_DIM +
                         nl0 + mm] = f2bf(acc[mf][nf][r]);
        }
    }
}

// ---------------------------------------------------------------------------
// Output GEMM: out_fp32 = ctx_bf16 * WoT^T. BM=128, BN=256 -> 64m x 4n =
// 256 blocks = 1.0 exact round. Same fine-phase core (2 phases x 8 MFMA).
// XCD chunking 8m x 4n: A 2MB + B 2MB both L2-resident per XCD.
// ---------------------------------------------------------------------------
__global__ __launch_bounds__(512, 2) void gemmo_k(const unsigned short* __restrict__ A,
                                                  const unsigned short* __restrict__ Bt,
                                                  float* __restrict__ C)
{
    __shared__ unsigned short sA[3 * 4096];        // 24KB
    __shared__ unsigned short sB[3 * 2 * 4096];    // 48KB
    const int t = threadIdx.x;
    const int bid = blockIdx.x;                    // 256 = 8 XCD * 32
    const int wg = (bid & 7) * 32 + (bid >> 3);
    const int mt = wg >> 2, nt = wg & 3;
    const int m0 = mt * 128, n0 = nt * 256;

    f32x4 acc[4][4];
#pragma unroll
    for (int i = 0; i < 4; ++i)
#pragma unroll
        for (int j = 0; j < 4; ++j) acc[i][j] = (f32x4){0.f, 0.f, 0.f, 0.f};

    gemm_core<4, 4, 1, 2>(A, Bt, sA, sB, m0, n0, t, acc);

    const int lane = t & 63, wid = t >> 6;
    const int mm = lane & 15, quad = lane >> 4;
    const int wm = wid >> 2, wn = wid & 3;

#pragma unroll
    for (int mf = 0; mf < 4; ++mf)
#pragma unroll
        for (int nf = 0; nf < 4; ++nf)
#pragma unroll
            for (int r = 0; r < 4; ++r)
                C[(size_t)(m0 + wm * 64 + mf * 16 + quad * 4 + r) * D_DIM +
                  n0 + wn * 64 + nf * 16 + mm] = acc[mf][nf][r];
}

// ---------------------------------------------------------------------------
// Fused causal flash attention, KVBLK=128 (two independent 64-key halves per
// barrier phase). R4 measured 2665 cy per 64-key tile with only ~450cy of
// issue work -> fixed cadence (barrier + serial chain) dominates; halving the
// barrier count amortizes it over 2x work and the two halves' QK/SM/PV chains
// overlap (independent regs, separate LDS planes). 512 thr (8 waves), 16
// q-rows/wave, block covers strips {qt, 15-qt}: uniform 17 k128-tiles.
// LDS: sK 2buf x 2plane x 8KB + sVT same + sP 16KB = 80KB -> 2 blocks/CU.
// sP reused serially by the halves (same-wave in-order DS, the property the
// K64 version already relied on). Planes keep gload_lds dest linear and the
// proven XOR bank swizzle unchanged.
// ---------------------------------------------------------------------------
__global__ __launch_bounds__(512, 4) void attn_k(const unsigned short* __restrict__ Q,
                                                 const unsigned short* __restrict__ K,
                                                 const unsigned short* __restrict__ Vt,
                                                 unsigned short* __restrict__ ctx)
{
    __shared__ unsigned short sK [2][2 * 4096];   // [buf][keyhalf][key64][hd]  2x16KB
    __shared__ unsigned short sVT[2][2 * 4096];   // [buf][keyhalf][hd][key64]  2x16KB
    __shared__ unsigned short sP [128 * 64];      // [qrow][key64]              16KB
    const int t = threadIdx.x;
    const int lane = t & 63, w = t >> 6;          // w = 0..7
    const int mm = lane & 15, quad = lane >> 4;
    const int pair = blockIdx.x, bh = blockIdx.y;
    const int b = bh >> 4, hh = bh & 15;
    const size_t rowbase = (size_t)b * S_LEN;
    const int coff = hh * HD;
    const unsigned short* Vh = Vt + (size_t)bh * HD * S_LEN;

    // staging geometry: 512 lanes cover one 64x128B plane per pass
    const int sc_ = t >> 3, sj = t & 7;
    const int sgk = sj ^ (sc_ & 7);               // XOR chunk swizzle

    u16x8 onesu;
#pragma unroll
    for (int j = 0; j < 8; ++j) onesu[j] = 0x3F80;   // bf16 1.0
    const bf16x8 ones = __builtin_bit_cast(bf16x8, onesu);

    for (int sidx = 0; sidx < 2; ++sidx) {
        const int qt = sidx ? (15 - pair) : pair;
        const int q0 = qt * 128;

        bf16x8 qf[2];
#pragma unroll
        for (int kk = 0; kk < 2; ++kk)
            qf[kk] = *(const bf16x8*)(Q + (rowbase + q0 + w * 16 + mm) * D_DIM
                                        + coff + kk * 32 + quad * 8);
        f32x4 o[4], lacc;
        lacc = (f32x4){0.f, 0.f, 0.f, 0.f};
#pragma unroll
        for (int hf = 0; hf < 4; ++hf) o[hf] = (f32x4){0.f, 0.f, 0.f, 0.f};

        const int nkt = qt + 1;                   // 128-key tiles
        const int qr = q0 + w * 16 + mm;          // this lane's q-row
        const int qrmax = q0 + w * 16 + 15;       // wave's max q-row
        const int m = w * 16 + mm;                // sP row

        // prologue: stage tile 0 (both 64-key planes of K and V^T) into buf 0
#pragma unroll
        for (int p = 0; p < 2; ++p) {
            gload16(K  + (rowbase + p * 64 + sc_) * D_DIM + coff + sgk * 8,
                    (void*)&sK[0][p * 4096 + t * 8]);
            gload16(Vh + (size_t)sc_ * S_LEN + p * 64 + sgk * 8,
                    (void*)&sVT[0][p * 4096 + t * 8]);
        }

        for (int kt = 0; kt < nkt; ++kt) {
            const int buf = kt & 1;
            __syncthreads();   // buf's loads drained (issued a full phase ago)
            if (kt + 1 < nkt) {
                const int k1 = (kt + 1) * 128;
#pragma unroll
                for (int p = 0; p < 2; ++p) {
                    gload16(K  + (rowbase + k1 + p * 64 + sc_) * D_DIM + coff + sgk * 8,
                            (void*)&sK[1 - buf][p * 4096 + t * 8]);
                    gload16(Vh + (size_t)sc_ * S_LEN + k1 + p * 64 + sgk * 8,
                            (void*)&sVT[1 - buf][p * 4096 + t * 8]);
                }
            }
#pragma unroll
            for (int h = 0; h < 2; ++h) {
                const int k0 = kt * 128 + h * 64;
                if (k0 > qrmax) continue;   // fully masked for this wave

                // S^T = K Q^T : A = K rows, B = Q rows
                f32x4 sacc[4];
#pragma unroll
                for (int kf = 0; kf < 4; ++kf) sacc[kf] = (f32x4){0.f, 0.f, 0.f, 0.f};
#pragma unroll
                for (int kk = 0; kk < 2; ++kk) {
                    bf16x8 ak[4];
#pragma unroll
                    for (int kf = 0; kf < 4; ++kf) {
                        int key = kf * 16 + mm;
                        int slot = (kk * 4 + quad) ^ (key & 7);
                        ak[kf] = *(const bf16x8*)&sK[buf][h * 4096 + key * 64 + slot * 8];
                    }
#pragma unroll
                    for (int kf = 0; kf < 4; ++kf)
                        sacc[kf] = __builtin_amdgcn_mfma_f32_16x16x32_bf16(ak[kf], qf[kk], sacc[kf], 0, 0, 0);
                }

                // p = exp2(s), causal mask -> 0, pack to wave-private sP rows
                const bool needmask = (k0 + 63) > (q0 + w * 16);
#pragma unroll
                for (int kf = 0; kf < 4; ++kf) {
                    float p[4];
#pragma unroll
                    for (int r = 0; r < 4; ++r) {
                        p[r] = __builtin_amdgcn_exp2f(sacc[kf][r]);
                        if (needmask && (k0 + kf * 16 + quad * 4 + r) > qr) p[r] = 0.f;
                    }
                    unsigned lo = pack2(p[0], p[1]), hi = pack2(p[2], p[3]);
                    int slot = (kf * 2 + (quad >> 1)) ^ (m & 7);
                    *(unsigned long long*)&sP[m * 64 + slot * 8 + (quad & 1) * 4] =
                        ((unsigned long long)hi << 32) | lo;
                }

                // O += P V ; l += P * ones
#pragma unroll
                for (int kk = 0; kk < 2; ++kk) {
                    bf16x8 pf, vf[4];
                    {
                        int slot = (kk * 4 + quad) ^ (m & 7);
                        pf = *(const bf16x8*)&sP[m * 64 + slot * 8];
                    }
#pragma unroll
                    for (int hf = 0; hf < 4; ++hf) {
                        int hd = hf * 16 + mm;
                        int slot = (kk * 4 + quad) ^ (hd & 7);
                        vf[hf] = *(const bf16x8*)&sVT[buf][h * 4096 + hd * 64 + slot * 8];
                    }
                    lacc = __builtin_amdgcn_mfma_f32_16x16x32_bf16(pf, ones, lacc, 0, 0, 0);
#pragma unroll
                    for (int hf = 0; hf < 4; ++hf)
                        o[hf] = __builtin_amdgcn_mfma_f32_16x16x32_bf16(pf, vf[hf], o[hf], 0, 0, 0);
                }
            }
        }
        __syncthreads();   // all compute done before next strip's prologue restages buf0

        // normalize (l already in C-layout) and store ctx
#pragma unroll
        for (int r = 0; r < 4; ++r) {
            float inv = 1.f / lacc[r];
            int row = q0 + w * 16 + quad * 4 + r;
#pragma unroll
            for (int hf = 0; hf < 4; ++hf)
                ctx[(rowbase + row) * D_DIM + coff + hf * 16 + mm] = f2bf(o[hf][r] * inv);
        }
    }
}

extern "C" void kernel_launch(void* const* d_in, const int* in_sizes, int n_in,
                              void* d_out, int out_size, void* d_ws, size_t ws_size,
                              hipStream_t stream)
{
    const float* x  = (const float*)d_in[0];
    const float* wq = (const float*)d_in[1];
    const float* wk = (const float*)d_in[2];
    const float* wv = (const float*)d_in[3];
    const float* wo = (const float*)d_in[4];

    const size_t XE = (size_t)M_ROWS * D_DIM;   // 8M elems
    const size_t WE = (size_t)D_DIM * D_DIM;    // 1M elems
    unsigned short* ws  = (unsigned short*)d_ws;
    unsigned short* xbf = ws;
    unsigned short* wt0 = xbf + XE;
    unsigned short* wt1 = wt0 + WE;
    unsigned short* wt2 = wt1 + WE;
    unsigned short* wt3 = wt2 + WE;
    unsigned short* qb  = wt3 + WE;
    unsigned short* kb  = qb + XE;
    unsigned short* vt  = kb + XE;      // V stored transposed per head
    unsigned short* cb  = vt + XE;      // ~80 MB total

    prep_k<<<dim3(4096 + 1024), 256, 0, stream>>>(x, wq, wk, wv, wo,
                                                  xbf, wt0, wt1, wt2, wt3);

    gemmqkv_k<<<dim3(256), 512, 0, stream>>>(xbf, wt0, qb, kb, vt);

    attn_k<<<dim3(8, BATCH * NH), 512, 0, stream>>>(qb, kb, vt, cb);

    gemmo_k<<<dim3(256), 512, 0, stream>>>(cb, wt3, (float*)d_out);
}

// Round 6
// 236.409 us; speedup vs baseline: 1.1147x; 1.0146x over previous
//
#include <hip/hip_runtime.h>

#define S_LEN 2048
#define D_DIM 1024
#define NH    16
#define HD    64
#define BATCH 4
#define M_ROWS 8192

typedef __attribute__((ext_vector_type(8))) short bf16x8;   // 8 bf16 = 4 VGPR
typedef __attribute__((ext_vector_type(4))) float f32x4;
typedef __attribute__((ext_vector_type(16))) float f32x16;
typedef __attribute__((ext_vector_type(8))) unsigned short u16x8;

__device__ __forceinline__ unsigned short f2bf(float f) {
    unsigned u = __builtin_bit_cast(unsigned, f);
    u = (u + 0x7fffu + ((u >> 16) & 1u)) >> 16;   // RNE
    return (unsigned short)u;
}

__device__ __forceinline__ void gload16(const void* g, void* l) {
    __builtin_amdgcn_global_load_lds((const __attribute__((address_space(1))) unsigned*)g,
                                     (__attribute__((address_space(3))) unsigned*)l,
                                     16, 0, 0);
}

template<int N> __device__ __forceinline__ void vmwait() {
    if constexpr (N == 0)      asm volatile("s_waitcnt vmcnt(0)" ::: "memory");
    else if constexpr (N == 3) asm volatile("s_waitcnt vmcnt(3)" ::: "memory");
    else if constexpr (N == 5) asm volatile("s_waitcnt vmcnt(5)" ::: "memory");
}

// pack two f32 -> bf16x2 (RNE) in one instruction
__device__ __forceinline__ unsigned cvtpk_bf16(float lo, float hi) {
    unsigned r;
    asm("v_cvt_pk_bf16_f32 %0, %1, %2" : "=v"(r) : "v"(lo), "v"(hi));
    return r;
}
// swap a[32:63] <-> b[0:31] (both operands updated)
__device__ __forceinline__ void pl32swap(unsigned &a, unsigned &b) {
    asm("v_permlane32_swap_b32 %0, %1" : "+v"(a), "+v"(b));
}

// ---------------------------------------------------------------------------
// Merged prep: blocks [0,4096) cast x fp32->bf16; blocks [4096,5120) build
// W^T bf16 (wq pre-scaled by 0.125*log2(e)). One launch instead of two.
// ---------------------------------------------------------------------------
__global__ __launch_bounds__(256) void prep_k(const float* __restrict__ x,
                                              const float* __restrict__ w0, const float* __restrict__ w1,
                                              const float* __restrict__ w2, const float* __restrict__ w3,
                                              unsigned short* __restrict__ xbf,
                                              unsigned short* __restrict__ o0, unsigned short* __restrict__ o1,
                                              unsigned short* __restrict__ o2, unsigned short* __restrict__ o3) {
    __shared__ float sT[64][65];
    const int t = threadIdx.x;
    if (blockIdx.x < 4096) {
        size_t i = (size_t)blockIdx.x * 256 + t;
        const float4* xf = (const float4*)x;
        float4 a = xf[2 * i], b = xf[2 * i + 1];
        u16x8 v;
        v[0] = f2bf(a.x); v[1] = f2bf(a.y); v[2] = f2bf(a.z); v[3] = f2bf(a.w);
        v[4] = f2bf(b.x); v[5] = f2bf(b.y); v[6] = f2bf(b.z); v[7] = f2bf(b.w);
        *(u16x8*)(xbf + i * 8) = v;
        return;
    }
    const int wb = blockIdx.x - 4096;          // 0..1023
    const int z = wb >> 8;                     // weight index
    const float* w; unsigned short* o;
    switch (z) {
        case 0: w = w0; o = o0; break;
        case 1: w = w1; o = o1; break;
        case 2: w = w2; o = o2; break;
        default: w = w3; o = o3; break;
    }
    const float sc = (z == 0) ? 0.18033688011112042f : 1.0f;
    const int n0 = (wb & 15) * 64, k0 = ((wb >> 4) & 15) * 64;
    const int r = t >> 4, cq = t & 15;
#pragma unroll
    for (int it = 0; it < 4; ++it) {
        int k = r + it * 16;
        float4 v = *(const float4*)&w[(size_t)(k0 + k) * D_DIM + n0 + cq * 4];
        sT[k][cq * 4 + 0] = v.x; sT[k][cq * 4 + 1] = v.y;
        sT[k][cq * 4 + 2] = v.z; sT[k][cq * 4 + 3] = v.w;
    }
    __syncthreads();
    const int n = t >> 2, ch = t & 3;
    union { unsigned short s[8]; uint4 v; } p0, p1;
#pragma unroll
    for (int j = 0; j < 8; ++j) p0.s[j] = f2bf(sT[ch * 16 + j][n] * sc);
#pragma unroll
    for (int j = 0; j < 8; ++j) p1.s[j] = f2bf(sT[ch * 16 + 8 + j][n] * sc);
    *(uint4*)&o[(size_t)(n0 + n) * D_DIM + k0 + ch * 16]     = p0.v;
    *(uint4*)&o[(size_t)(n0 + n) * D_DIM + k0 + ch * 16 + 8] = p1.v;
}

// ---------------------------------------------------------------------------
// Fine-phase GEMM core. Tile = (MFRAG*32) x (NFRAG*64), BK=32. 8 waves as
// 2M x 4N: per-wave output = MFRAG*16 rows x NFRAG*16 cols, acc[MFRAG][NFRAG].
// 3-slot LDS ring, 1 full tile always in flight across barriers (T4).
// XOR chunk swizzle both sides -> measured 0 bank conflicts (R2-R5).
// ---------------------------------------------------------------------------
template<int MFRAG, int NFRAG, int AGLD, int BGLD>
__device__ __forceinline__ void gemm_core(const unsigned short* __restrict__ A,
                                          const unsigned short* __restrict__ Bt,
                                          unsigned short* __restrict__ sA,
                                          unsigned short* __restrict__ sB,
                                          int m0, int n0, int t,
                                          f32x4 (&acc)[MFRAG][NFRAG])
{
    constexpr int NGLD  = AGLD + BGLD;
    constexpr int ASLOT = AGLD * 4096;     // elems per ring slot
    constexpr int BSLOT = BGLD * 4096;
    constexpr int NPH   = MFRAG / 2;       // phases per K-32 tile

    const int lane = t & 63, wid = t >> 6;
    const int mm = lane & 15, quad = lane >> 4;
    const int wm = wid >> 2, wn = wid & 3;

    const int sr = t >> 2;
    const int sg = (t & 3) ^ ((sr >> 1) & 3);
    const unsigned short* asrc = A  + (size_t)(m0 + sr) * D_DIM + sg * 8;
    const unsigned short* bsrc = Bt + (size_t)(n0 + sr) * D_DIM + sg * 8;
    unsigned short* dA = sA + t * 8;
    unsigned short* dB = sB + t * 8;

    const int al = wm * (MFRAG * 16) + mm;
    const int bl = wn * (NFRAG * 16) + mm;
    const int xs = quad ^ ((mm >> 1) & 3);

    // prologue: tiles 0,1 into slots 0,1; confirm tile 0, keep tile 1 in flight
#pragma unroll
    for (int pt = 0; pt < 2; ++pt) {
        const int ko = pt * 32;
#pragma unroll
        for (int i = 0; i < AGLD; ++i)
            gload16(asrc + (size_t)i * 128 * D_DIM + ko, dA + pt * ASLOT + i * 4096);
#pragma unroll
        for (int i = 0; i < BGLD; ++i)
            gload16(bsrc + (size_t)i * 128 * D_DIM + ko, dB + pt * BSLOT + i * 4096);
    }
    vmwait<NGLD>();
    __builtin_amdgcn_s_barrier();

    int sRead = 0, sWrite = 2;
    for (int T = 0; T < 32; ++T) {
        const int soA = sRead * ASLOT, soB = sRead * BSLOT;
        const int woA = sWrite * ASLOT, woB = sWrite * BSLOT;
        const int ko = (T + 2) * 32;
        const bool st = (T <= 29);

        bf16x8 bv[NFRAG];
#pragma unroll
        for (int p = 0; p < NPH; ++p) {
            if (p == 0) {
#pragma unroll
                for (int nf = 0; nf < NFRAG; ++nf)
                    bv[nf] = *(const bf16x8*)&sB[soB + (bl + nf * 16) * 32 + xs * 8];
            }
            bf16x8 af0 = *(const bf16x8*)&sA[soA + (al + (2 * p) * 16) * 32 + xs * 8];
            bf16x8 af1 = *(const bf16x8*)&sA[soA + (al + (2 * p + 1) * 16) * 32 + xs * 8];

            if (st) {
                if (p == 0) {
#pragma unroll
                    for (int i = 0; i < AGLD; ++i)
                        gload16(asrc + (size_t)i * 128 * D_DIM + ko, dA + woA + i * 4096);
                } else {
#pragma unroll
                    for (int i = 0; i < BGLD; ++i)
                        if ((i % (NPH - 1)) == p - 1)
                            gload16(bsrc + (size_t)i * 128 * D_DIM + ko, dB + woB + i * 4096);
                }
            }

            __builtin_amdgcn_s_barrier();
            asm volatile("s_waitcnt lgkmcnt(0)" ::: "memory");
            __builtin_amdgcn_s_setprio(1);
#pragma unroll
            for (int nf = 0; nf < NFRAG; ++nf) {
                acc[2 * p][nf]     = __builtin_amdgcn_mfma_f32_16x16x32_bf16(af0, bv[nf], acc[2 * p][nf], 0, 0, 0);
                acc[2 * p + 1][nf] = __builtin_amdgcn_mfma_f32_16x16x32_bf16(af1, bv[nf], acc[2 * p + 1][nf], 0, 0, 0);
            }
            __builtin_amdgcn_s_setprio(0);
            if (p == NPH - 1) {
                if (T <= 29)      vmwait<NGLD>();   // tile T+1 confirmed, T+2 in flight
                else if (T == 30) vmwait<0>();      // drain: tile 31 confirmed
            }
            __builtin_amdgcn_s_barrier();
        }

        sRead  = (sRead  == 2) ? 0 : sRead + 1;
        sWrite = (sWrite == 2) ? 0 : sWrite + 1;
    }
}

// ---------------------------------------------------------------------------
// Fused QKV GEMM: BM=256, BN=384 -> grid 32m x 8n = 256 blocks = 1.0 exact
// round, 153.6 FLOP/staged-byte. B^T = [Wq^T|Wk^T|Wv^T] contiguous; epilogue
// routes per 16-wide fragment. LDS 120KB (3-slot ring). XCD chunking:
// 4 m-tiles x all n per XCD -> A panel 2MB L2-resident.
// ---------------------------------------------------------------------------
__global__ __launch_bounds__(512, 2) void gemmqkv_k(const unsigned short* __restrict__ A,
                                                    const unsigned short* __restrict__ Bt,
                                                    unsigned short* __restrict__ qb,
                                                    unsigned short* __restrict__ kb,
                                                    unsigned short* __restrict__ vt)
{
    __shared__ unsigned short sA[3 * 2 * 4096];    // 48KB
    __shared__ unsigned short sB[3 * 3 * 4096];    // 72KB
    const int t = threadIdx.x;
    const int bid = blockIdx.x;                    // 256 = 8 XCD * 32
    const int wg = (bid & 7) * 32 + (bid >> 3);
    const int mt = wg >> 3, nt = wg & 7;
    const int m0 = mt * 256, n0 = nt * 384;

    f32x4 acc[8][6];
#pragma unroll
    for (int i = 0; i < 8; ++i)
#pragma unroll
        for (int j = 0; j < 6; ++j) acc[i][j] = (f32x4){0.f, 0.f, 0.f, 0.f};

    gemm_core<8, 6, 2, 3>(A, Bt, sA, sB, m0, n0, t, acc);

    const int lane = t & 63, wid = t >> 6;
    const int mm = lane & 15, quad = lane >> 4;
    const int wm = wid >> 2, wn = wid & 3;

#pragma unroll
    for (int nf = 0; nf < 6; ++nf) {
        const int c0 = n0 + wn * 96 + nf * 16;     // 16-aligned -> widx uniform
        const int widx = c0 >> 10, nl0 = c0 & 1023;
        if (widx == 2) {
            // V: write transposed per head (16-wide frag never crosses a head)
            const int h = nl0 >> 6, hd = (nl0 & 63) + mm;
#pragma unroll
            for (int mf = 0; mf < 8; ++mf) {
                int rglob = m0 + wm * 128 + mf * 16 + quad * 4;
                int bb = rglob >> 11, ss = rglob & (S_LEN - 1);
                union { unsigned short s[4]; unsigned long long ll; } pk;
#pragma unroll
                for (int r = 0; r < 4; ++r) pk.s[r] = f2bf(acc[mf][nf][r]);
                *(unsigned long long*)&vt[((size_t)(bb * NH + h) * HD + hd) * S_LEN + ss] = pk.ll;
            }
        } else {
            unsigned short* outp = widx ? kb : qb;
#pragma unroll
            for (int mf = 0; mf < 8; ++mf)
#pragma unroll
                for (int r = 0; r < 4; ++r)
                    outp[(size_t)(m0 + wm * 128 + mf * 16 + quad * 4 + r) * D_DIM +
                         nl0 + mm] = f2bf(acc[mf][nf][r]);
        }
    }
}

// ---------------------------------------------------------------------------
// Output GEMM: out_fp32 = ctx_bf16 * WoT^T. BM=128, BN=256 -> 64m x 4n =
// 256 blocks = 1.0 exact round. Same fine-phase core (2 phases x 8 MFMA).
// XCD chunking 8m x 4n: A 2MB + B 2MB both L2-resident per XCD.
// ---------------------------------------------------------------------------
__global__ __launch_bounds__(512, 2) void gemmo_k(const unsigned short* __restrict__ A,
                                                  const unsigned short* __restrict__ Bt,
                                                  float* __restrict__ C)
{
    __shared__ unsigned short sA[3 * 4096];        // 24KB
    __shared__ unsigned short sB[3 * 2 * 4096];    // 48KB
    const int t = threadIdx.x;
    const int bid = blockIdx.x;                    // 256 = 8 XCD * 32
    const int wg = (bid & 7) * 32 + (bid >> 3);
    const int mt = wg >> 2, nt = wg & 3;
    const int m0 = mt * 128, n0 = nt * 256;

    f32x4 acc[4][4];
#pragma unroll
    for (int i = 0; i < 4; ++i)
#pragma unroll
        for (int j = 0; j < 4; ++j) acc[i][j] = (f32x4){0.f, 0.f, 0.f, 0.f};

    gemm_core<4, 4, 1, 2>(A, Bt, sA, sB, m0, n0, t, acc);

    const int lane = t & 63, wid = t >> 6;
    const int mm = lane & 15, quad = lane >> 4;
    const int wm = wid >> 2, wn = wid & 3;

#pragma unroll
    for (int mf = 0; mf < 4; ++mf)
#pragma unroll
        for (int nf = 0; nf < 4; ++nf)
#pragma unroll
            for (int r = 0; r < 4; ++r)
                C[(size_t)(m0 + wm * 64 + mf * 16 + quad * 4 + r) * D_DIM +
                  n0 + wn * 64 + nf * 16 + mm] = acc[mf][nf][r];
}

// ---------------------------------------------------------------------------
// Fused causal flash attention, 32x32x16 MFMA + fully in-register P (T12).
// R5 diagnosis: LDS-throughput-bound (~68% LDS pipe util; 18 b128 reads +
// sP round-trip per 16 q-rows per k64). This version: 4 waves x 32 q-rows
// (QBLK=128), swapped QK^T (A=K, B=Q) so lane holds S^T[key][q=lane&31];
// P->bf16 B-frags built with 16 cvt_pk + 8 permlane32_swap (no sP, no LDS);
// PV computes O^T = V^T * P^T. Per wave per k64: 16 ds_read_b128 + 20 MFMA
// (2x the FLOP per LDS byte). l via ones-A MFMA -> normalization uses the
// same bf16-quantized P as PV (exact consistency).
// Grid 512 = 64 bh x 8 causal pairs (qt,15-qt) = 2 blocks/CU; LDS 32KB.
// bh-clustered XCD map: each XCD's 8 bh -> 4MB K/V L2-resident.
// Bank math: a-frag reads have 8 lanes per 16B slot under the chunk swizzle
// = the 8-cy b128 minimum (conflict-free).
// ---------------------------------------------------------------------------
__global__ __launch_bounds__(256, 2) void attn_k(const unsigned short* __restrict__ Q,
                                                 const unsigned short* __restrict__ K,
                                                 const unsigned short* __restrict__ Vt,
                                                 unsigned short* __restrict__ ctx)
{
    __shared__ unsigned short sK [2][64 * 64];   // [buf][key][hd]   2x8KB
    __shared__ unsigned short sVT[2][64 * 64];   // [buf][hd][key]   2x8KB
    const int t = threadIdx.x;
    const int lane = t & 63, w = t >> 6;          // w = 0..3
    const int m5 = lane & 31, h = lane >> 5;
    const int m7 = m5 & 7;
    const int bid = blockIdx.x;                   // 512
    const int ii = bid >> 3;
    const int bh = (bid & 7) * 8 + (ii >> 3);     // 8 bh per XCD
    const int pair = ii & 7;
    const int b = bh >> 4, hh = bh & 15;
    const size_t rowbase = (size_t)b * S_LEN;
    const int coff = hh * HD;
    const unsigned short* Vh = Vt + (size_t)bh * HD * S_LEN;

    // staging: thread covers rows sc and sc+32, chunk sj; (sc+32)&7 == sc&7
    const int sc = t >> 3, sj = t & 7;
    const int sg = (sj ^ (sc & 7)) * 8;

    u16x8 onesu;
#pragma unroll
    for (int j = 0; j < 8; ++j) onesu[j] = 0x3F80;   // bf16 1.0
    const bf16x8 ones = __builtin_bit_cast(bf16x8, onesu);

    for (int sidx = 0; sidx < 2; ++sidx) {
        const int qt = sidx ? (15 - pair) : pair;
        const int q0 = qt * 128;
        const int qrw = q0 + w * 32;              // wave q base
        const int qr  = qrw + m5;                 // this lane's q-row (= MFMA col)

        // Q in regs: B[k=hd][col=q]: lane needs Q[qr][s*16 + h*8 + 0..7]
        bf16x8 qf[4];
#pragma unroll
        for (int s = 0; s < 4; ++s)
            qf[s] = *(const bf16x8*)(Q + (rowbase + qr) * D_DIM + coff + s * 16 + h * 8);

        f32x16 o0, o1, l16;
#pragma unroll
        for (int r = 0; r < 16; ++r) { o0[r] = 0.f; o1[r] = 0.f; l16[r] = 0.f; }

        const int nkt = 2 * qt + 2;

        // prologue: stage tile 0 -> buf 0
        gload16(K  + (rowbase + sc) * D_DIM + coff + sg,      (void*)&sK[0][t * 8]);
        gload16(K  + (rowbase + sc + 32) * D_DIM + coff + sg, (void*)&sK[0][2048 + t * 8]);
        gload16(Vh + (size_t)sc * S_LEN + sg,                 (void*)&sVT[0][t * 8]);
        gload16(Vh + (size_t)(sc + 32) * S_LEN + sg,          (void*)&sVT[0][2048 + t * 8]);

        for (int kt = 0; kt < nkt; ++kt) {
            const int buf = kt & 1;
            __syncthreads();   // buf's loads drained
            if (kt + 1 < nkt) {
                const int k1 = (kt + 1) * 64;
                gload16(K  + (rowbase + k1 + sc) * D_DIM + coff + sg,      (void*)&sK[1 - buf][t * 8]);
                gload16(K  + (rowbase + k1 + sc + 32) * D_DIM + coff + sg, (void*)&sK[1 - buf][2048 + t * 8]);
                gload16(Vh + (size_t)sc * S_LEN + k1 + sg,                 (void*)&sVT[1 - buf][t * 8]);
                gload16(Vh + (size_t)(sc + 32) * S_LEN + k1 + sg,          (void*)&sVT[1 - buf][2048 + t * 8]);
            }
            const int k0 = kt * 64;
            if (k0 > qrw + 31) continue;   // fully masked for this wave

            // S^T = K Q^T : A=K rows (key = kf*32 + m5), k=hd
            f32x16 s0, s1;
#pragma unroll
            for (int r = 0; r < 16; ++r) { s0[r] = 0.f; s1[r] = 0.f; }
            __builtin_amdgcn_s_setprio(1);
#pragma unroll
            for (int s = 0; s < 4; ++s) {
                const int sl = ((2 * s + h) ^ m7) * 8;
                bf16x8 ak0 = *(const bf16x8*)&sK[buf][m5 * 64 + sl];
                bf16x8 ak1 = *(const bf16x8*)&sK[buf][(32 + m5) * 64 + sl];
                s0 = __builtin_amdgcn_mfma_f32_32x32x16_bf16(ak0, qf[s], s0, 0, 0, 0);
                s1 = __builtin_amdgcn_mfma_f32_32x32x16_bf16(ak1, qf[s], s1, 0, 0, 0);
            }
            __builtin_amdgcn_s_setprio(0);

            // p = exp2(s) (wq pre-scaled), mask, pack to PV B-frags in regs.
            // Lane reg r holds key_local = (r&3)+8*(r>>2)+4h within kf block.
            // swap(A0,B0),(A1,B1) -> frag sigma0 keys {16*0+8h+j}; (C,D) -> sigma1.
            const bool needmask = (k0 + 63) > qrw;
            bf16x8 pb[4];
#pragma unroll
            for (int kf = 0; kf < 2; ++kf) {
                unsigned pw[8];
#pragma unroll
                for (int j = 0; j < 8; ++j) {
                    float plo = __builtin_amdgcn_exp2f(kf ? s1[2 * j] : s0[2 * j]);
                    float phi = __builtin_amdgcn_exp2f(kf ? s1[2 * j + 1] : s0[2 * j + 1]);
                    if (needmask) {
                        const int kb_ = k0 + kf * 32 + 4 * h;
                        const int r0 = 2 * j, r1 = 2 * j + 1;
                        if (kb_ + (r0 & 3) + 8 * (r0 >> 2) > qr) plo = 0.f;
                        if (kb_ + (r1 & 3) + 8 * (r1 >> 2) > qr) phi = 0.f;
                    }
                    pw[j] = cvtpk_bf16(plo, phi);
                }
                pl32swap(pw[0], pw[2]);
                pl32swap(pw[1], pw[3]);
                pl32swap(pw[4], pw[6]);
                pl32swap(pw[5], pw[7]);
                union { unsigned u[4]; bf16x8 v; } f0, f1;
                f0.u[0] = pw[0]; f0.u[1] = pw[1]; f0.u[2] = pw[2]; f0.u[3] = pw[3];
                f1.u[0] = pw[4]; f1.u[1] = pw[5]; f1.u[2] = pw[6]; f1.u[3] = pw[7];
                pb[kf * 2 + 0] = f0.v;
                pb[kf * 2 + 1] = f1.v;
            }

            // O^T += V^T P^T ; l += ones P^T  (same quantized P as PV)
            __builtin_amdgcn_s_setprio(1);
#pragma unroll
            for (int s = 0; s < 4; ++s) {
                const int sl = ((2 * s + h) ^ m7) * 8;
                bf16x8 vf0 = *(const bf16x8*)&sVT[buf][m5 * 64 + sl];
                bf16x8 vf1 = *(const bf16x8*)&sVT[buf][(32 + m5) * 64 + sl];
                l16 = __builtin_amdgcn_mfma_f32_32x32x16_bf16(ones, pb[s], l16, 0, 0, 0);
                o0  = __builtin_amdgcn_mfma_f32_32x32x16_bf16(vf0,  pb[s], o0, 0, 0, 0);
                o1  = __builtin_amdgcn_mfma_f32_32x32x16_bf16(vf1,  pb[s], o1, 0, 0, 0);
            }
            __builtin_amdgcn_s_setprio(0);
        }
        __syncthreads();   // all compute done before next strip's prologue restages buf0

        // normalize and store: O^T[hd][q]: reg rg*4+r -> hd = hf*32 + 8*rg + 4h + r
        const float linv = 1.f / l16[0];
#pragma unroll
        for (int hf = 0; hf < 2; ++hf) {
#pragma unroll
            for (int rg = 0; rg < 4; ++rg) {
                union { unsigned short s4[4]; unsigned long long ll; } pk4;
#pragma unroll
                for (int r = 0; r < 4; ++r)
                    pk4.s4[r] = f2bf((hf ? o1[rg * 4 + r] : o0[rg * 4 + r]) * linv);
                *(unsigned long long*)&ctx[(rowbase + qr) * D_DIM + coff + hf * 32 + 8 * rg + 4 * h] = pk4.ll;
            }
        }
    }
}

extern "C" void kernel_launch(void* const* d_in, const int* in_sizes, int n_in,
                              void* d_out, int out_size, void* d_ws, size_t ws_size,
                              hipStream_t stream)
{
    const float* x  = (const float*)d_in[0];
    const float* wq = (const float*)d_in[1];
    const float* wk = (const float*)d_in[2];
    const float* wv = (const float*)d_in[3];
    const float* wo = (const float*)d_in[4];

    const size_t XE = (size_t)M_ROWS * D_DIM;   // 8M elems
    const size_t WE = (size_t)D_DIM * D_DIM;    // 1M elems
    unsigned short* ws  = (unsigned short*)d_ws;
    unsigned short* xbf = ws;
    unsigned short* wt0 = xbf + XE;
    unsigned short* wt1 = wt0 + WE;
    unsigned short* wt2 = wt1 + WE;
    unsigned short* wt3 = wt2 + WE;
    unsigned short* qb  = wt3 + WE;
    unsigned short* kb  = qb + XE;
    unsigned short* vt  = kb + XE;      // V stored transposed per head
    unsigned short* cb  = vt + XE;      // ~80 MB total

    prep_k<<<dim3(4096 + 1024), 256, 0, stream>>>(x, wq, wk, wv, wo,
                                                  xbf, wt0, wt1, wt2, wt3);

    gemmqkv_k<<<dim3(256), 512, 0, stream>>>(xbf, wt0, qb, kb, vt);

    attn_k<<<dim3(512), 256, 0, stream>>>(qb, kb, vt, cb);

    gemmo_k<<<dim3(256), 512, 0, stream>>>(cb, wt3, (float*)d_out);
}